// Round 1
// baseline (1828.909 us; speedup 1.0000x reference)
//
#include <hip/hip_runtime.h>
#include <hip/hip_bf16.h>

// Mamba block fp32 baseline.
// Pipeline:
//  1) xz = x @ W_in.T                  (2048 x 4096, K=2048)   -> ws.xz
//  2) u  = silu(causal_conv4(xz[:, :2048]))                    -> ws.u
//  3) x_dbl = u @ W_xproj.T            (2048 x 160,  K=2048)   -> ws.xdbl
//  4) dt = softplus(x_dbl[:, :128] @ W_dt.T + b_dt) (2048x2048, K=128) -> ws.dt
//  5) selective scan over L (+ fused  y=(ys+u*D)*silu(z))      -> ws.yact
//  6) out = yact @ W_out.T             (2048 x 2048, K=2048)   -> d_out

#define D_MODEL 2048
#define D_STATE 16
#define KER 4
#define DT_RANK 128
#define B_SZ 2
#define SEQ 1024
#define BL (B_SZ * SEQ)          // 2048 rows
#define XPROJ_N (DT_RANK + 2 * D_STATE)  // 160

// ---------------- generic fp32 NT GEMM: C[m][n] = sum_k A[m,k] * W[n,k] ----------------
#define BM 64
#define BN 64
#define BKT 32

__device__ __forceinline__ float softplusf(float x) {
    return (x > 20.f) ? x : log1pf(__expf(x));
}

// EPI: 0 = store raw, 1 = softplus(acc + bias[col])
template <int EPI>
__global__ __launch_bounds__(256) void gemm_nt(
    const float* __restrict__ A, int lda,
    const float* __restrict__ W, int ldw,
    float* __restrict__ C, int ldc,
    const float* __restrict__ bias,
    int M, int N, int K)
{
    __shared__ float As[BKT][BM + 4];
    __shared__ float Ws[BKT][BN + 4];

    const int tid = threadIdx.x;
    const int bm = blockIdx.y * BM;
    const int bn = blockIdx.x * BN;
    const int tx = tid & 15;   // col group 0..15
    const int ty = tid >> 4;   // row group 0..15

    float acc[4][4] = {};

    for (int k0 = 0; k0 < K; k0 += BKT) {
        // stage A tile (64 rows x 32 k), transposed into As[k][m]
        #pragma unroll
        for (int i = 0; i < 2; ++i) {
            int f = tid + i * 256;
            int row = f >> 3;       // 0..63
            int kq  = f & 7;        // float4 index within 32 k
            float4 v = *reinterpret_cast<const float4*>(
                &A[(size_t)(bm + row) * lda + k0 + kq * 4]);
            As[kq * 4 + 0][row] = v.x;
            As[kq * 4 + 1][row] = v.y;
            As[kq * 4 + 2][row] = v.z;
            As[kq * 4 + 3][row] = v.w;
        }
        // stage W tile (64 rows x 32 k), transposed into Ws[k][n]; guard N tail
        #pragma unroll
        for (int i = 0; i < 2; ++i) {
            int f = tid + i * 256;
            int row = f >> 3;
            int kq  = f & 7;
            int gn = bn + row;
            float4 v = make_float4(0.f, 0.f, 0.f, 0.f);
            if (gn < N) {
                v = *reinterpret_cast<const float4*>(
                    &W[(size_t)gn * ldw + k0 + kq * 4]);
            }
            Ws[kq * 4 + 0][row] = v.x;
            Ws[kq * 4 + 1][row] = v.y;
            Ws[kq * 4 + 2][row] = v.z;
            Ws[kq * 4 + 3][row] = v.w;
        }
        __syncthreads();

        #pragma unroll
        for (int kk = 0; kk < BKT; ++kk) {
            float4 a4 = *reinterpret_cast<const float4*>(&As[kk][ty * 4]);
            float4 w4 = *reinterpret_cast<const float4*>(&Ws[kk][tx * 4]);
            float a[4] = {a4.x, a4.y, a4.z, a4.w};
            float w[4] = {w4.x, w4.y, w4.z, w4.w};
            #pragma unroll
            for (int i = 0; i < 4; ++i)
                #pragma unroll
                for (int j = 0; j < 4; ++j)
                    acc[i][j] = fmaf(a[i], w[j], acc[i][j]);
        }
        __syncthreads();
    }

    // epilogue
    #pragma unroll
    for (int i = 0; i < 4; ++i) {
        int gm = bm + ty * 4 + i;
        #pragma unroll
        for (int j = 0; j < 4; ++j) {
            int gn = bn + tx * 4 + j;
            if (gn < N) {
                float v = acc[i][j];
                if (EPI == 1) v = softplusf(v + bias[gn]);
                C[(size_t)gm * ldc + gn] = v;
            }
        }
    }
}

// ---------------- depthwise causal conv (K=4) + SiLU ----------------
__global__ __launch_bounds__(256) void conv_silu_kernel(
    const float* __restrict__ xz,      // (BL, 2*D_MODEL), u_raw = cols [0, D)
    const float* __restrict__ conv_w,  // (D, 4)
    const float* __restrict__ conv_b,  // (D,)
    float* __restrict__ u)             // (BL, D)
{
    int idx = blockIdx.x * blockDim.x + threadIdx.x;  // over B*L*D
    if (idx >= BL * D_MODEL) return;
    int d  = idx & (D_MODEL - 1);
    int bl = idx >> 11;                // / D_MODEL
    int l  = bl & (SEQ - 1);
    int b  = bl >> 10;

    float acc = conv_b[d];
    #pragma unroll
    for (int k = 0; k < KER; ++k) {
        int ls = l - (KER - 1) + k;
        if (ls >= 0) {
            acc = fmaf(conv_w[d * KER + k],
                       xz[(size_t)(b * SEQ + ls) * (2 * D_MODEL) + d], acc);
        }
    }
    float s = acc / (1.f + __expf(-acc));   // silu
    u[(size_t)idx] = s;
}

// ---------------- selective scan (sequential over L) + fused gate ----------------
// Wave layout: 64 lanes = 4 channels x 16 states. Block = 4 waves = 16 channels.
// Grid = B * (D/16) = 256 blocks.
__global__ __launch_bounds__(256) void scan_kernel(
    const float* __restrict__ dt,     // (BL, D)
    const float* __restrict__ xdbl,   // (BL, 160): [dt_r 128 | B 16 | C 16]
    const float* __restrict__ xz,     // (BL, 4096): z = cols [2048, 4096)
    const float* __restrict__ u,      // (BL, D)
    const float* __restrict__ A_log,  // (D, 16)
    const float* __restrict__ Dskip,  // (D,)
    float* __restrict__ yact)         // (BL, D)
{
    const int tid  = threadIdx.x;
    const int lane = tid & 63;
    const int wave = tid >> 6;       // 0..3
    const int n    = lane & 15;      // state index
    const int ci   = lane >> 4;      // 0..3 channel-in-wave
    const int blk  = blockIdx.x;     // 0..255
    const int b    = blk >> 7;       // 128 blocks per batch
    const int d    = (blk & 127) * 16 + wave * 4 + ci;

    const float Adn = -__expf(A_log[d * D_STATE + n]);
    const float Dk  = Dskip[d];

    float h = 0.f;
    const size_t rowbase = (size_t)b * SEQ;
    for (int t = 0; t < SEQ; ++t) {
        const size_t row = rowbase + t;
        const float dtv = dt[row * D_MODEL + d];
        const float uv  = u[row * D_MODEL + d];
        const float Bv  = xdbl[row * XPROJ_N + DT_RANK + n];
        const float Cv  = xdbl[row * XPROJ_N + DT_RANK + D_STATE + n];

        const float dA = __expf(dtv * Adn);
        h = fmaf(dA, h, dtv * Bv * uv);
        float p = h * Cv;
        p += __shfl_xor(p, 8);
        p += __shfl_xor(p, 4);
        p += __shfl_xor(p, 2);
        p += __shfl_xor(p, 1);
        if (n == 0) {
            const float zv = xz[row * (2 * D_MODEL) + D_MODEL + d];
            const float yv = p + uv * Dk;
            const float sz = zv / (1.f + __expf(-zv));
            yact[row * D_MODEL + d] = yv * sz;
        }
    }
}

// ---------------- launch ----------------
extern "C" void kernel_launch(void* const* d_in, const int* in_sizes, int n_in,
                              void* d_out, int out_size, void* d_ws, size_t ws_size,
                              hipStream_t stream) {
    const float* x       = (const float*)d_in[0];
    const float* W_in    = (const float*)d_in[1];
    const float* conv_w  = (const float*)d_in[2];
    const float* conv_b  = (const float*)d_in[3];
    const float* W_xproj = (const float*)d_in[4];
    const float* W_dt    = (const float*)d_in[5];
    const float* b_dt    = (const float*)d_in[6];
    const float* A_log   = (const float*)d_in[7];
    const float* Dskip   = (const float*)d_in[8];
    const float* W_out   = (const float*)d_in[9];
    float* out = (float*)d_out;

    float* ws = (float*)d_ws;
    // workspace layout (in floats)
    float* xz   = ws;                         // 2048 x 4096 = 8M
    float* u    = ws + (size_t)8 * 1024 * 1024;   // 2048 x 2048 = 4M
    float* xdbl = ws + (size_t)12 * 1024 * 1024;  // 2048 x 160  (reserve 512K)
    float* dt   = ws + (size_t)12 * 1024 * 1024 + 512 * 1024; // 4M
    float* yact = dt + (size_t)4 * 1024 * 1024;   // 4M

    // 1) xz = x @ W_in.T   (M=2048, N=4096, K=2048)
    {
        dim3 grid(2 * D_MODEL / BN, BL / BM);
        gemm_nt<0><<<grid, 256, 0, stream>>>(x, D_MODEL, W_in, D_MODEL,
                                             xz, 2 * D_MODEL, nullptr,
                                             BL, 2 * D_MODEL, D_MODEL);
    }
    // 2) conv + silu
    {
        int total = BL * D_MODEL;
        conv_silu_kernel<<<total / 256, 256, 0, stream>>>(xz, conv_w, conv_b, u);
    }
    // 3) x_dbl = u @ W_xproj.T  (M=2048, N=160, K=2048)
    {
        dim3 grid((XPROJ_N + BN - 1) / BN, BL / BM);
        gemm_nt<0><<<grid, 256, 0, stream>>>(u, D_MODEL, W_xproj, D_MODEL,
                                             xdbl, XPROJ_N, nullptr,
                                             BL, XPROJ_N, D_MODEL);
    }
    // 4) dt = softplus(x_dbl[:, :128] @ W_dt.T + b_dt)  (M=2048, N=2048, K=128)
    {
        dim3 grid(D_MODEL / BN, BL / BM);
        gemm_nt<1><<<grid, 256, 0, stream>>>(xdbl, XPROJ_N, W_dt, DT_RANK,
                                             dt, D_MODEL, b_dt,
                                             BL, D_MODEL, DT_RANK);
    }
    // 5) selective scan + fused output gate
    {
        scan_kernel<<<B_SZ * (D_MODEL / 16), 256, 0, stream>>>(
            dt, xdbl, xz, u, A_log, Dskip, yact);
    }
    // 6) out = yact @ W_out.T  (M=2048, N=2048, K=2048)
    {
        dim3 grid(D_MODEL / BN, BL / BM);
        gemm_nt<0><<<grid, 256, 0, stream>>>(yact, D_MODEL, W_out, D_MODEL,
                                             out, D_MODEL, nullptr,
                                             BL, D_MODEL, D_MODEL);
    }
}

// Round 4
// 528.493 us; speedup vs baseline: 3.4606x; 3.4606x over previous
//
#include <hip/hip_runtime.h>
#include <hip/hip_bf16.h>

// Mamba block — split-bf16 MFMA GEMMs + chunked parallel scan.
//  1) xz = x @ W_in.T      (2048x4096, K=2048)  MFMA split-bf16  -> ws.xz (fp32)
//  2) u  = silu(conv4(xz[:, :2048]))                             -> ws.u
//  3) x_dbl = u @ W_xproj.T (2048x160, K=2048)  fp32 VALU        -> ws.xdbl
//  4) dt = softplus(x_dbl[:,:128] @ W_dt.T + b_dt) fp32 VALU     -> ws.dt
//  5) chunked scan (S1 local / S2 combine / S3 replay+gate)      -> ws.yact
//  6) out = yact @ W_out.T (2048x2048, K=2048)  MFMA split-bf16  -> d_out

#define D_MODEL 2048
#define D_STATE 16
#define KER 4
#define DT_RANK 128
#define B_SZ 2
#define SEQ 1024
#define BL (B_SZ * SEQ)
#define XPROJ_N (DT_RANK + 2 * D_STATE)  // 160
#define NC 32
#define TC (SEQ / NC)

using f32x4  = __attribute__((ext_vector_type(4))) float;
using bf16x8 = __attribute__((ext_vector_type(8))) __bf16;
using bf16x4 = __attribute__((ext_vector_type(4))) __bf16;

__device__ __forceinline__ float softplusf(float x) {
    return (x > 20.f) ? x : log1pf(__expf(x));
}
__device__ __forceinline__ float siluf(float x) {
    return x / (1.f + __expf(-x));
}

// ---------------- fp32 -> (hi, lo) bf16 plane split ----------------
__global__ __launch_bounds__(256) void split_kernel(
    const float* __restrict__ src,
    __bf16* __restrict__ hi, __bf16* __restrict__ lo, int n4)
{
    int i = blockIdx.x * 256 + threadIdx.x;
    if (i >= n4) return;
    float4 v = *reinterpret_cast<const float4*>(&src[(size_t)i * 4]);
    bf16x4 hv, lv;
    float f[4] = {v.x, v.y, v.z, v.w};
    #pragma unroll
    for (int j = 0; j < 4; ++j) {
        __bf16 h = (__bf16)f[j];
        hv[j] = h;
        lv[j] = (__bf16)(f[j] - (float)h);
    }
    *reinterpret_cast<bf16x4*>(&hi[(size_t)i * 4]) = hv;
    *reinterpret_cast<bf16x4*>(&lo[(size_t)i * 4]) = lv;
}

// ---------------- split-bf16 MFMA NT GEMM ----------------
// C[m][n] = sum_k A[m,k]*W[n,k], A ~ Ah+Al, W ~ Wh+Wl (drop Al*Wl).
// 128x128 tile, BK=64, 4 waves (2x2 of 64x64), mfma_f32_16x16x32_bf16.
// LDS linear row-major [128][64] bf16 per plane; XOR swizzle slot^=(row&7)
// applied on BOTH global source (pre-swizzle) and ds_read (rule #21).
__global__ __launch_bounds__(256, 2) void gemm_bf3(
    const __bf16* __restrict__ Ah, const __bf16* __restrict__ Al,
    const __bf16* __restrict__ Wh, const __bf16* __restrict__ Wl,
    float* __restrict__ C, int N_, int K)
{
    __shared__ __align__(16) __bf16 lds[4 * 128 * 64];
    __bf16* sAh = lds;
    __bf16* sAl = lds + 8192;
    __bf16* sWh = lds + 16384;
    __bf16* sWl = lds + 24576;

    const int tid = threadIdx.x;
    const int bm = blockIdx.y * 128;
    const int bn = blockIdx.x * 128;
    const int w  = tid >> 6;
    const int l  = tid & 63;
    const int wr = (w >> 1) * 64;
    const int wc = (w & 1) * 64;
    const int fr = l & 15;
    const int fq = l >> 4;

    f32x4 acc[4][4] = {};

    for (int k0 = 0; k0 < K; k0 += 64) {
        #pragma unroll
        for (int i = 0; i < 4; ++i) {
            const int f  = i * 256 + tid;   // 16B chunk id 0..1023
            const int r  = f >> 3;          // tile row 0..127
            const int ss = f & 7;           // dest slot
            const int gs = ss ^ (r & 7);    // pre-swizzled source slot
            const size_t ga = (size_t)(bm + r) * K + k0 + gs * 8;
            const size_t gw = (size_t)(bn + r) * K + k0 + gs * 8;
            __builtin_amdgcn_global_load_lds(
                (const __attribute__((address_space(1))) void*)(Ah + ga),
                (__attribute__((address_space(3))) void*)(sAh + (size_t)f * 8), 16, 0, 0);
            __builtin_amdgcn_global_load_lds(
                (const __attribute__((address_space(1))) void*)(Al + ga),
                (__attribute__((address_space(3))) void*)(sAl + (size_t)f * 8), 16, 0, 0);
            __builtin_amdgcn_global_load_lds(
                (const __attribute__((address_space(1))) void*)(Wh + gw),
                (__attribute__((address_space(3))) void*)(sWh + (size_t)f * 8), 16, 0, 0);
            __builtin_amdgcn_global_load_lds(
                (const __attribute__((address_space(1))) void*)(Wl + gw),
                (__attribute__((address_space(3))) void*)(sWl + (size_t)f * 8), 16, 0, 0);
        }
        __syncthreads();

        #pragma unroll
        for (int ks = 0; ks < 2; ++ks) {
            bf16x8 ah[4], al[4], wh[4], wl[4];
            #pragma unroll
            for (int t = 0; t < 4; ++t) {
                const int ra = wr + t * 16 + fr;
                const int sa = (ks * 4 + fq) ^ (ra & 7);
                ah[t] = *reinterpret_cast<const bf16x8*>(&sAh[ra * 64 + sa * 8]);
                al[t] = *reinterpret_cast<const bf16x8*>(&sAl[ra * 64 + sa * 8]);
                const int rw = wc + t * 16 + fr;
                const int sw = (ks * 4 + fq) ^ (rw & 7);
                wh[t] = *reinterpret_cast<const bf16x8*>(&sWh[rw * 64 + sw * 8]);
                wl[t] = *reinterpret_cast<const bf16x8*>(&sWl[rw * 64 + sw * 8]);
            }
            #pragma unroll
            for (int mt = 0; mt < 4; ++mt)
                #pragma unroll
                for (int nt = 0; nt < 4; ++nt) {
                    acc[mt][nt] = __builtin_amdgcn_mfma_f32_16x16x32_bf16(
                        ah[mt], wh[nt], acc[mt][nt], 0, 0, 0);
                    acc[mt][nt] = __builtin_amdgcn_mfma_f32_16x16x32_bf16(
                        ah[mt], wl[nt], acc[mt][nt], 0, 0, 0);
                    acc[mt][nt] = __builtin_amdgcn_mfma_f32_16x16x32_bf16(
                        al[mt], wh[nt], acc[mt][nt], 0, 0, 0);
                }
        }
        __syncthreads();
    }

    // C/D layout (m89-verified): col = lane&15, row = (lane>>4)*4 + reg
    #pragma unroll
    for (int mt = 0; mt < 4; ++mt)
        #pragma unroll
        for (int nt = 0; nt < 4; ++nt)
            #pragma unroll
            for (int j = 0; j < 4; ++j)
                C[(size_t)(bm + wr + mt * 16 + fq * 4 + j) * N_
                  + bn + wc + nt * 16 + fr] = acc[mt][nt][j];
}

// ---------------- fp32 NT GEMM (small shapes: x_dbl, dt) ----------------
#define BM 64
#define BN 64
#define BKT 32

template <int EPI>
__global__ __launch_bounds__(256) void gemm_nt(
    const float* __restrict__ A, int lda,
    const float* __restrict__ W, int ldw,
    float* __restrict__ C, int ldc,
    const float* __restrict__ bias,
    int M, int N, int K)
{
    __shared__ float As[BKT][BM + 4];
    __shared__ float Ws[BKT][BN + 4];

    const int tid = threadIdx.x;
    const int bm = blockIdx.y * BM;
    const int bn = blockIdx.x * BN;
    const int tx = tid & 15;
    const int ty = tid >> 4;

    float acc[4][4] = {};

    for (int k0 = 0; k0 < K; k0 += BKT) {
        #pragma unroll
        for (int i = 0; i < 2; ++i) {
            int f = tid + i * 256;
            int row = f >> 3;
            int kq  = f & 7;
            float4 v = *reinterpret_cast<const float4*>(
                &A[(size_t)(bm + row) * lda + k0 + kq * 4]);
            As[kq * 4 + 0][row] = v.x;
            As[kq * 4 + 1][row] = v.y;
            As[kq * 4 + 2][row] = v.z;
            As[kq * 4 + 3][row] = v.w;
        }
        #pragma unroll
        for (int i = 0; i < 2; ++i) {
            int f = tid + i * 256;
            int row = f >> 3;
            int kq  = f & 7;
            int gn = bn + row;
            float4 v = make_float4(0.f, 0.f, 0.f, 0.f);
            if (gn < N) {
                v = *reinterpret_cast<const float4*>(
                    &W[(size_t)gn * ldw + k0 + kq * 4]);
            }
            Ws[kq * 4 + 0][row] = v.x;
            Ws[kq * 4 + 1][row] = v.y;
            Ws[kq * 4 + 2][row] = v.z;
            Ws[kq * 4 + 3][row] = v.w;
        }
        __syncthreads();

        #pragma unroll
        for (int kk = 0; kk < BKT; ++kk) {
            float4 a4 = *reinterpret_cast<const float4*>(&As[kk][ty * 4]);
            float4 w4 = *reinterpret_cast<const float4*>(&Ws[kk][tx * 4]);
            float a[4] = {a4.x, a4.y, a4.z, a4.w};
            float wv[4] = {w4.x, w4.y, w4.z, w4.w};
            #pragma unroll
            for (int i = 0; i < 4; ++i)
                #pragma unroll
                for (int j = 0; j < 4; ++j)
                    acc[i][j] = fmaf(a[i], wv[j], acc[i][j]);
        }
        __syncthreads();
    }

    #pragma unroll
    for (int i = 0; i < 4; ++i) {
        int gm = bm + ty * 4 + i;
        #pragma unroll
        for (int j = 0; j < 4; ++j) {
            int gn = bn + tx * 4 + j;
            if (gn < N) {
                float v = acc[i][j];
                if (EPI == 1) v = softplusf(v + bias[gn]);
                C[(size_t)gm * ldc + gn] = v;
            }
        }
    }
}

// ---------------- depthwise causal conv (K=4) + SiLU ----------------
__global__ __launch_bounds__(256) void conv_silu_kernel(
    const float* __restrict__ xz,
    const float* __restrict__ conv_w,
    const float* __restrict__ conv_b,
    float* __restrict__ u)
{
    int idx = blockIdx.x * blockDim.x + threadIdx.x;
    if (idx >= BL * D_MODEL) return;
    int d  = idx & (D_MODEL - 1);
    int bl = idx >> 11;
    int l  = bl & (SEQ - 1);
    int b  = bl >> 10;

    float acc = conv_b[d];
    #pragma unroll
    for (int k = 0; k < KER; ++k) {
        int ls = l - (KER - 1) + k;
        if (ls >= 0) {
            acc = fmaf(conv_w[d * KER + k],
                       xz[(size_t)(b * SEQ + ls) * (2 * D_MODEL) + d], acc);
        }
    }
    u[(size_t)idx] = siluf(acc);
}

// ---------------- chunked selective scan ----------------
__global__ __launch_bounds__(256) void scan_part1(
    const float* __restrict__ dt,
    const float* __restrict__ xdbl,
    const float* __restrict__ u,
    const float* __restrict__ A_log,
    float* __restrict__ PH,
    float* __restrict__ Hend)
{
    const int tid = threadIdx.x;
    const int d   = blockIdx.x * 256 + tid;
    const int bc  = blockIdx.y;
    const int b   = bc >> 5;
    const int c   = bc & (NC - 1);

    float A[16];
    #pragma unroll
    for (int q = 0; q < 4; ++q) {
        float4 v = *reinterpret_cast<const float4*>(&A_log[d * 16 + q * 4]);
        A[q*4+0] = -__expf(v.x); A[q*4+1] = -__expf(v.y);
        A[q*4+2] = -__expf(v.z); A[q*4+3] = -__expf(v.w);
    }
    float h[16] = {};
    float P[16];
    #pragma unroll
    for (int n = 0; n < 16; ++n) P[n] = 1.f;

    const size_t row0 = (size_t)b * SEQ + c * TC;
    for (int t = 0; t < TC; ++t) {
        const size_t row = row0 + t;
        const float dtv = dt[row * D_MODEL + d];
        const float uv  = u[row * D_MODEL + d];
        float Bv[16];
        const float4* Bp = reinterpret_cast<const float4*>(&xdbl[row * XPROJ_N + DT_RANK]);
        #pragma unroll
        for (int q = 0; q < 4; ++q) {
            float4 v = Bp[q];
            Bv[q*4+0] = v.x; Bv[q*4+1] = v.y; Bv[q*4+2] = v.z; Bv[q*4+3] = v.w;
        }
        const float dtu = dtv * uv;
        #pragma unroll
        for (int n = 0; n < 16; ++n) {
            float dA = __expf(dtv * A[n]);
            h[n] = fmaf(dA, h[n], dtu * Bv[n]);
            P[n] *= dA;
        }
    }
    const size_t off = ((size_t)bc * D_MODEL + d) * 16;
    #pragma unroll
    for (int q = 0; q < 4; ++q) {
        *reinterpret_cast<float4*>(&PH[off + q*4])   =
            make_float4(P[q*4+0], P[q*4+1], P[q*4+2], P[q*4+3]);
        *reinterpret_cast<float4*>(&Hend[off + q*4]) =
            make_float4(h[q*4+0], h[q*4+1], h[q*4+2], h[q*4+3]);
    }
}

__global__ __launch_bounds__(256) void scan_part2(
    float* __restrict__ PH,
    const float* __restrict__ Hend)
{
    const int g  = blockIdx.x * 256 + threadIdx.x;
    const int b  = g >> 15;
    const int dn = g & 32767;
    float h = 0.f;
    #pragma unroll
    for (int c = 0; c < NC; ++c) {
        const size_t off = ((size_t)(b * NC + c) * D_MODEL * 16) + dn;
        const float p  = PH[off];
        const float he = Hend[off];
        PH[off] = h;
        h = fmaf(p, h, he);
    }
}

__global__ __launch_bounds__(256) void scan_part3(
    const float* __restrict__ dt,
    const float* __restrict__ xdbl,
    const float* __restrict__ xz,
    const float* __restrict__ u,
    const float* __restrict__ A_log,
    const float* __restrict__ Dskip,
    const float* __restrict__ PH,
    float* __restrict__ yact)
{
    const int tid = threadIdx.x;
    const int d   = blockIdx.x * 256 + tid;
    const int bc  = blockIdx.y;
    const int b   = bc >> 5;
    const int c   = bc & (NC - 1);

    float A[16];
    #pragma unroll
    for (int q = 0; q < 4; ++q) {
        float4 v = *reinterpret_cast<const float4*>(&A_log[d * 16 + q * 4]);
        A[q*4+0] = -__expf(v.x); A[q*4+1] = -__expf(v.y);
        A[q*4+2] = -__expf(v.z); A[q*4+3] = -__expf(v.w);
    }
    float h[16];
    const size_t off = ((size_t)bc * D_MODEL + d) * 16;
    #pragma unroll
    for (int q = 0; q < 4; ++q) {
        float4 v = *reinterpret_cast<const float4*>(&PH[off + q*4]);
        h[q*4+0] = v.x; h[q*4+1] = v.y; h[q*4+2] = v.z; h[q*4+3] = v.w;
    }
    const float Dk = Dskip[d];

    const size_t row0 = (size_t)b * SEQ + c * TC;
    for (int t = 0; t < TC; ++t) {
        const size_t row = row0 + t;
        const float dtv = dt[row * D_MODEL + d];
        const float uv  = u[row * D_MODEL + d];
        float Bv[16], Cv[16];
        const float4* Bp = reinterpret_cast<const float4*>(&xdbl[row * XPROJ_N + DT_RANK]);
        const float4* Cp = reinterpret_cast<const float4*>(&xdbl[row * XPROJ_N + DT_RANK + D_STATE]);
        #pragma unroll
        for (int q = 0; q < 4; ++q) {
            float4 v = Bp[q];
            Bv[q*4+0] = v.x; Bv[q*4+1] = v.y; Bv[q*4+2] = v.z; Bv[q*4+3] = v.w;
            float4 wv = Cp[q];
            Cv[q*4+0] = wv.x; Cv[q*4+1] = wv.y; Cv[q*4+2] = wv.z; Cv[q*4+3] = wv.w;
        }
        const float dtu = dtv * uv;
        float y = 0.f;
        #pragma unroll
        for (int n = 0; n < 16; ++n) {
            float dA = __expf(dtv * A[n]);
            h[n] = fmaf(dA, h[n], dtu * Bv[n]);
            y = fmaf(h[n], Cv[n], y);
        }
        const float zv = xz[row * (2 * D_MODEL) + D_MODEL + d];
        const float yv = y + uv * Dk;
        yact[row * D_MODEL + d] = yv * siluf(zv);
    }
}

// ---------------- launch ----------------
extern "C" void kernel_launch(void* const* d_in, const int* in_sizes, int n_in,
                              void* d_out, int out_size, void* d_ws, size_t ws_size,
                              hipStream_t stream) {
    const float* x       = (const float*)d_in[0];
    const float* W_in    = (const float*)d_in[1];
    const float* conv_w  = (const float*)d_in[2];
    const float* conv_b  = (const float*)d_in[3];
    const float* W_xproj = (const float*)d_in[4];
    const float* W_dt    = (const float*)d_in[5];
    const float* b_dt    = (const float*)d_in[6];
    const float* A_log   = (const float*)d_in[7];
    const float* Dskip   = (const float*)d_in[8];
    const float* W_out   = (const float*)d_in[9];
    float* out = (float*)d_out;

    float* ws = (float*)d_ws;
    const size_t M1 = 1024 * 1024;
    float* xz   = ws;                        // 8M fp32
    float* u    = ws + 8 * M1;               // 4M
    float* xdbl = ws + 12 * M1;              // 0.5M
    float* dt   = ws + 12 * M1 + 512 * 1024; // 4M
    float* yact = dt + 4 * M1;               // 4M
    float* PH   = yact + 4 * M1;             // 2M
    float* Hend = PH + 2 * M1;               // 2M  (ends at 24.5M floats)

    __bf16* planes = (__bf16*)(ws + 25 * M1);
    __bf16* xh  = planes;                    // 4M bf16
    __bf16* xl  = xh + 4 * M1;               // 4M
    __bf16* wih = xl + 4 * M1;               // 8M
    __bf16* wil = wih + 8 * M1;              // 8M  (ends at 25M + 12M floats)
    // reuse regions (stream-ordered, producers after consumers are done):
    __bf16* woh = wih;                       // 4M (W_in planes dead after GEMM1)
    __bf16* wol = wih + 4 * M1;              // 4M
    __bf16* yh  = xh;                        // 4M (x planes dead after GEMM1)
    __bf16* yl  = xl;                        // 4M

    // split x and W_in to bf16 hi/lo planes
    split_kernel<<<(BL * D_MODEL / 4 + 255) / 256, 256, 0, stream>>>(x, xh, xl, BL * D_MODEL / 4);
    split_kernel<<<(2 * D_MODEL * D_MODEL / 4 + 255) / 256, 256, 0, stream>>>(
        W_in, wih, wil, 2 * D_MODEL * D_MODEL / 4);

    // 1) xz = x @ W_in.T  (MFMA split-bf16)
    {
        dim3 grid(2 * D_MODEL / 128, BL / 128);
        gemm_bf3<<<grid, 256, 0, stream>>>(xh, xl, wih, wil, xz, 2 * D_MODEL, D_MODEL);
    }
    // 2) conv + silu
    conv_silu_kernel<<<BL * D_MODEL / 256, 256, 0, stream>>>(xz, conv_w, conv_b, u);

    // split W_out (reuses W_in plane region)
    split_kernel<<<(D_MODEL * D_MODEL / 4 + 255) / 256, 256, 0, stream>>>(
        W_out, woh, wol, D_MODEL * D_MODEL / 4);

    // 3) x_dbl = u @ W_xproj.T  (fp32)
    {
        dim3 grid((XPROJ_N + BN - 1) / BN, BL / BM);
        gemm_nt<0><<<grid, 256, 0, stream>>>(u, D_MODEL, W_xproj, D_MODEL,
                                             xdbl, XPROJ_N, nullptr,
                                             BL, XPROJ_N, D_MODEL);
    }
    // 4) dt = softplus(x_dbl[:, :128] @ W_dt.T + b_dt)  (fp32)
    {
        dim3 grid(D_MODEL / BN, BL / BM);
        gemm_nt<1><<<grid, 256, 0, stream>>>(xdbl, XPROJ_N, W_dt, DT_RANK,
                                             dt, D_MODEL, b_dt,
                                             BL, D_MODEL, DT_RANK);
    }
    // 5) chunked scan
    {
        dim3 grid(D_MODEL / 256, B_SZ * NC);
        scan_part1<<<grid, 256, 0, stream>>>(dt, xdbl, u, A_log, PH, Hend);
        scan_part2<<<B_SZ * D_MODEL * 16 / 256, 256, 0, stream>>>(PH, Hend);
        scan_part3<<<grid, 256, 0, stream>>>(dt, xdbl, xz, u, A_log, Dskip, PH, yact);
    }
    // split yact (reuses x plane region)
    split_kernel<<<(BL * D_MODEL / 4 + 255) / 256, 256, 0, stream>>>(yact, yh, yl, BL * D_MODEL / 4);

    // 6) out = yact @ W_out.T  (MFMA split-bf16)
    {
        dim3 grid(D_MODEL / 128, BL / 128);
        gemm_bf3<<<grid, 256, 0, stream>>>(yh, yl, woh, wol, out, D_MODEL, D_MODEL);
    }
}

// Round 5
// 430.021 us; speedup vs baseline: 4.2531x; 1.2290x over previous
//
#include <hip/hip_runtime.h>
#include <hip/hip_bf16.h>

// Mamba block — split-bf16 MFMA GEMMs + chunked parallel scan + split-K x_dbl.
//  1) xz = x @ W_in.T      (2048x4096, K=2048)  MFMA split-bf16  -> ws.xz (fp32)
//  2) u  = silu(conv4(xz[:, :2048]))                             -> ws.u
//  3) x_dbl = u @ W_xproj.T (2048x160, K=2048)  fp32 split-K(8)  -> ws.xdbl
//  4) dt = softplus(x_dbl[:,:128] @ W_dt.T + b_dt) fp32 VALU     -> ws.dt
//  5) chunked scan (S1 local / S2 combine / S3 replay+gate)      -> ws.yact
//  6) out = yact @ W_out.T (2048x2048, K=2048)  MFMA split-bf16  -> d_out

#define D_MODEL 2048
#define D_STATE 16
#define KER 4
#define DT_RANK 128
#define B_SZ 2
#define SEQ 1024
#define BL (B_SZ * SEQ)
#define XPROJ_N (DT_RANK + 2 * D_STATE)  // 160
#define NC 32
#define TC (SEQ / NC)

using f32x4  = __attribute__((ext_vector_type(4))) float;
using bf16x8 = __attribute__((ext_vector_type(8))) __bf16;
using bf16x4 = __attribute__((ext_vector_type(4))) __bf16;

__device__ __forceinline__ float softplusf(float x) {
    return (x > 20.f) ? x : log1pf(__expf(x));
}
__device__ __forceinline__ float siluf(float x) {
    return x / (1.f + __expf(-x));
}

// ---------------- fp32 -> (hi, lo) bf16 plane split ----------------
__global__ __launch_bounds__(256) void split_kernel(
    const float* __restrict__ src,
    __bf16* __restrict__ hi, __bf16* __restrict__ lo, int n4)
{
    int i = blockIdx.x * 256 + threadIdx.x;
    if (i >= n4) return;
    float4 v = *reinterpret_cast<const float4*>(&src[(size_t)i * 4]);
    bf16x4 hv, lv;
    float f[4] = {v.x, v.y, v.z, v.w};
    #pragma unroll
    for (int j = 0; j < 4; ++j) {
        __bf16 h = (__bf16)f[j];
        hv[j] = h;
        lv[j] = (__bf16)(f[j] - (float)h);
    }
    *reinterpret_cast<bf16x4*>(&hi[(size_t)i * 4]) = hv;
    *reinterpret_cast<bf16x4*>(&lo[(size_t)i * 4]) = lv;
}

// ---------------- split-bf16 MFMA NT GEMM ----------------
// C[m][n] = sum_k A[m,k]*W[n,k], A ~ Ah+Al, W ~ Wh+Wl (drop Al*Wl).
// 128x128 tile, BK=64, 4 waves (2x2 of 64x64), mfma_f32_16x16x32_bf16.
// LDS linear row-major [128][64] bf16 per plane; XOR swizzle slot^=(row&7)
// applied on BOTH global source (pre-swizzle) and ds_read (rule #21).
__global__ __launch_bounds__(256, 2) void gemm_bf3(
    const __bf16* __restrict__ Ah, const __bf16* __restrict__ Al,
    const __bf16* __restrict__ Wh, const __bf16* __restrict__ Wl,
    float* __restrict__ C, int N_, int K)
{
    __shared__ __align__(16) __bf16 lds[4 * 128 * 64];
    __bf16* sAh = lds;
    __bf16* sAl = lds + 8192;
    __bf16* sWh = lds + 16384;
    __bf16* sWl = lds + 24576;

    const int tid = threadIdx.x;
    const int bm = blockIdx.y * 128;
    const int bn = blockIdx.x * 128;
    const int w  = tid >> 6;
    const int l  = tid & 63;
    const int wr = (w >> 1) * 64;
    const int wc = (w & 1) * 64;
    const int fr = l & 15;
    const int fq = l >> 4;

    f32x4 acc[4][4] = {};

    for (int k0 = 0; k0 < K; k0 += 64) {
        #pragma unroll
        for (int i = 0; i < 4; ++i) {
            const int f  = i * 256 + tid;   // 16B chunk id 0..1023
            const int r  = f >> 3;          // tile row 0..127
            const int ss = f & 7;           // dest slot
            const int gs = ss ^ (r & 7);    // pre-swizzled source slot
            const size_t ga = (size_t)(bm + r) * K + k0 + gs * 8;
            const size_t gw = (size_t)(bn + r) * K + k0 + gs * 8;
            __builtin_amdgcn_global_load_lds(
                (const __attribute__((address_space(1))) void*)(Ah + ga),
                (__attribute__((address_space(3))) void*)(sAh + (size_t)f * 8), 16, 0, 0);
            __builtin_amdgcn_global_load_lds(
                (const __attribute__((address_space(1))) void*)(Al + ga),
                (__attribute__((address_space(3))) void*)(sAl + (size_t)f * 8), 16, 0, 0);
            __builtin_amdgcn_global_load_lds(
                (const __attribute__((address_space(1))) void*)(Wh + gw),
                (__attribute__((address_space(3))) void*)(sWh + (size_t)f * 8), 16, 0, 0);
            __builtin_amdgcn_global_load_lds(
                (const __attribute__((address_space(1))) void*)(Wl + gw),
                (__attribute__((address_space(3))) void*)(sWl + (size_t)f * 8), 16, 0, 0);
        }
        __syncthreads();

        #pragma unroll
        for (int ks = 0; ks < 2; ++ks) {
            bf16x8 ah[4], al[4], wh[4], wl[4];
            #pragma unroll
            for (int t = 0; t < 4; ++t) {
                const int ra = wr + t * 16 + fr;
                const int sa = (ks * 4 + fq) ^ (ra & 7);
                ah[t] = *reinterpret_cast<const bf16x8*>(&sAh[ra * 64 + sa * 8]);
                al[t] = *reinterpret_cast<const bf16x8*>(&sAl[ra * 64 + sa * 8]);
                const int rw = wc + t * 16 + fr;
                const int sw = (ks * 4 + fq) ^ (rw & 7);
                wh[t] = *reinterpret_cast<const bf16x8*>(&sWh[rw * 64 + sw * 8]);
                wl[t] = *reinterpret_cast<const bf16x8*>(&sWl[rw * 64 + sw * 8]);
            }
            #pragma unroll
            for (int mt = 0; mt < 4; ++mt)
                #pragma unroll
                for (int nt = 0; nt < 4; ++nt) {
                    acc[mt][nt] = __builtin_amdgcn_mfma_f32_16x16x32_bf16(
                        ah[mt], wh[nt], acc[mt][nt], 0, 0, 0);
                    acc[mt][nt] = __builtin_amdgcn_mfma_f32_16x16x32_bf16(
                        ah[mt], wl[nt], acc[mt][nt], 0, 0, 0);
                    acc[mt][nt] = __builtin_amdgcn_mfma_f32_16x16x32_bf16(
                        al[mt], wh[nt], acc[mt][nt], 0, 0, 0);
                }
        }
        __syncthreads();
    }

    // C/D layout (m89-verified): col = lane&15, row = (lane>>4)*4 + reg
    #pragma unroll
    for (int mt = 0; mt < 4; ++mt)
        #pragma unroll
        for (int nt = 0; nt < 4; ++nt)
            #pragma unroll
            for (int j = 0; j < 4; ++j)
                C[(size_t)(bm + wr + mt * 16 + fq * 4 + j) * N_
                  + bn + wc + nt * 16 + fr] = acc[mt][nt][j];
}

// ---------------- fp32 NT GEMM (dt GEMM) ----------------
#define BM 64
#define BN 64
#define BKT 32

template <int EPI>
__global__ __launch_bounds__(256) void gemm_nt(
    const float* __restrict__ A, int lda,
    const float* __restrict__ W, int ldw,
    float* __restrict__ C, int ldc,
    const float* __restrict__ bias,
    int M, int N, int K)
{
    __shared__ float As[BKT][BM + 4];
    __shared__ float Ws[BKT][BN + 4];

    const int tid = threadIdx.x;
    const int bm = blockIdx.y * BM;
    const int bn = blockIdx.x * BN;
    const int tx = tid & 15;
    const int ty = tid >> 4;

    float acc[4][4] = {};

    for (int k0 = 0; k0 < K; k0 += BKT) {
        #pragma unroll
        for (int i = 0; i < 2; ++i) {
            int f = tid + i * 256;
            int row = f >> 3;
            int kq  = f & 7;
            float4 v = *reinterpret_cast<const float4*>(
                &A[(size_t)(bm + row) * lda + k0 + kq * 4]);
            As[kq * 4 + 0][row] = v.x;
            As[kq * 4 + 1][row] = v.y;
            As[kq * 4 + 2][row] = v.z;
            As[kq * 4 + 3][row] = v.w;
        }
        #pragma unroll
        for (int i = 0; i < 2; ++i) {
            int f = tid + i * 256;
            int row = f >> 3;
            int kq  = f & 7;
            int gn = bn + row;
            float4 v = make_float4(0.f, 0.f, 0.f, 0.f);
            if (gn < N) {
                v = *reinterpret_cast<const float4*>(
                    &W[(size_t)gn * ldw + k0 + kq * 4]);
            }
            Ws[kq * 4 + 0][row] = v.x;
            Ws[kq * 4 + 1][row] = v.y;
            Ws[kq * 4 + 2][row] = v.z;
            Ws[kq * 4 + 3][row] = v.w;
        }
        __syncthreads();

        #pragma unroll
        for (int kk = 0; kk < BKT; ++kk) {
            float4 a4 = *reinterpret_cast<const float4*>(&As[kk][ty * 4]);
            float4 w4 = *reinterpret_cast<const float4*>(&Ws[kk][tx * 4]);
            float a[4] = {a4.x, a4.y, a4.z, a4.w};
            float wv[4] = {w4.x, w4.y, w4.z, w4.w};
            #pragma unroll
            for (int i = 0; i < 4; ++i)
                #pragma unroll
                for (int j = 0; j < 4; ++j)
                    acc[i][j] = fmaf(a[i], wv[j], acc[i][j]);
        }
        __syncthreads();
    }

    #pragma unroll
    for (int i = 0; i < 4; ++i) {
        int gm = bm + ty * 4 + i;
        #pragma unroll
        for (int j = 0; j < 4; ++j) {
            int gn = bn + tx * 4 + j;
            if (gn < N) {
                float v = acc[i][j];
                if (EPI == 1) v = softplusf(v + bias[gn]);
                C[(size_t)gm * ldc + gn] = v;
            }
        }
    }
}

// ---------------- split-K x_dbl GEMM: M=2048, N=160, K=2048 ----------------
// Round-4 profile: old single-pass grid was 96 blocks -> Occupancy 4.2%,
// VALUBusy 7.6%, 157 us. Split-K(8) + BN=32 -> grid (5,32,8)=1280 blocks.
#define XBM 64
#define XBN 32
#define XKS 8
#define XKC (D_MODEL / XKS)   // 256

__global__ __launch_bounds__(256) void xdbl_partial(
    const float* __restrict__ A,      // u (BL, D_MODEL)
    const float* __restrict__ W,      // W_xproj (160, D_MODEL)
    float* __restrict__ P)            // (XKS, BL, 160)
{
    __shared__ float As[BKT][XBM + 4];
    __shared__ float Ws[BKT][XBN + 4];

    const int tid = threadIdx.x;
    const int bm = blockIdx.y * XBM;
    const int bn = blockIdx.x * XBN;
    const int ks = blockIdx.z;
    const int tx = tid & 7;           // 8 col groups x4
    const int ty = tid >> 3;          // 32 row groups x2

    float acc[2][4] = {};

    const int kend = (ks + 1) * XKC;
    for (int k0 = ks * XKC; k0 < kend; k0 += BKT) {
        #pragma unroll
        for (int i = 0; i < 2; ++i) {
            int f = tid + i * 256;
            int row = f >> 3;
            int kq  = f & 7;
            float4 v = *reinterpret_cast<const float4*>(
                &A[(size_t)(bm + row) * D_MODEL + k0 + kq * 4]);
            As[kq * 4 + 0][row] = v.x;
            As[kq * 4 + 1][row] = v.y;
            As[kq * 4 + 2][row] = v.z;
            As[kq * 4 + 3][row] = v.w;
        }
        {
            int row = tid >> 3;       // 0..31
            int kq  = tid & 7;
            float4 v = *reinterpret_cast<const float4*>(
                &W[(size_t)(bn + row) * D_MODEL + k0 + kq * 4]);
            Ws[kq * 4 + 0][row] = v.x;
            Ws[kq * 4 + 1][row] = v.y;
            Ws[kq * 4 + 2][row] = v.z;
            Ws[kq * 4 + 3][row] = v.w;
        }
        __syncthreads();

        #pragma unroll
        for (int kk = 0; kk < BKT; ++kk) {
            float a0 = As[kk][ty * 2 + 0];
            float a1 = As[kk][ty * 2 + 1];
            float4 w4 = *reinterpret_cast<const float4*>(&Ws[kk][tx * 4]);
            float wv[4] = {w4.x, w4.y, w4.z, w4.w};
            #pragma unroll
            for (int j = 0; j < 4; ++j) {
                acc[0][j] = fmaf(a0, wv[j], acc[0][j]);
                acc[1][j] = fmaf(a1, wv[j], acc[1][j]);
            }
        }
        __syncthreads();
    }

    #pragma unroll
    for (int i = 0; i < 2; ++i) {
        const int gm = bm + ty * 2 + i;
        #pragma unroll
        for (int j = 0; j < 4; ++j) {
            const int gn = bn + tx * 4 + j;
            P[((size_t)ks * BL + gm) * XPROJ_N + gn] = acc[i][j];
        }
    }
}

__global__ __launch_bounds__(256) void xdbl_reduce(
    const float* __restrict__ P, float* __restrict__ xdbl)
{
    const int i = blockIdx.x * 256 + threadIdx.x;   // float4 index
    const int n4 = BL * XPROJ_N / 4;
    if (i >= n4) return;
    float4 s = *reinterpret_cast<const float4*>(&P[(size_t)i * 4]);
    #pragma unroll
    for (int ks = 1; ks < XKS; ++ks) {
        float4 v = *reinterpret_cast<const float4*>(
            &P[(size_t)ks * BL * XPROJ_N + (size_t)i * 4]);
        s.x += v.x; s.y += v.y; s.z += v.z; s.w += v.w;
    }
    *reinterpret_cast<float4*>(&xdbl[(size_t)i * 4]) = s;
}

// ---------------- depthwise causal conv (K=4) + SiLU ----------------
__global__ __launch_bounds__(256) void conv_silu_kernel(
    const float* __restrict__ xz,
    const float* __restrict__ conv_w,
    const float* __restrict__ conv_b,
    float* __restrict__ u)
{
    int idx = blockIdx.x * blockDim.x + threadIdx.x;
    if (idx >= BL * D_MODEL) return;
    int d  = idx & (D_MODEL - 1);
    int bl = idx >> 11;
    int l  = bl & (SEQ - 1);
    int b  = bl >> 10;

    float acc = conv_b[d];
    #pragma unroll
    for (int k = 0; k < KER; ++k) {
        int ls = l - (KER - 1) + k;
        if (ls >= 0) {
            acc = fmaf(conv_w[d * KER + k],
                       xz[(size_t)(b * SEQ + ls) * (2 * D_MODEL) + d], acc);
        }
    }
    u[(size_t)idx] = siluf(acc);
}

// ---------------- chunked selective scan ----------------
__global__ __launch_bounds__(256) void scan_part1(
    const float* __restrict__ dt,
    const float* __restrict__ xdbl,
    const float* __restrict__ u,
    const float* __restrict__ A_log,
    float* __restrict__ PH,
    float* __restrict__ Hend)
{
    const int tid = threadIdx.x;
    const int d   = blockIdx.x * 256 + tid;
    const int bc  = blockIdx.y;
    const int b   = bc >> 5;
    const int c   = bc & (NC - 1);

    float A[16];
    #pragma unroll
    for (int q = 0; q < 4; ++q) {
        float4 v = *reinterpret_cast<const float4*>(&A_log[d * 16 + q * 4]);
        A[q*4+0] = -__expf(v.x); A[q*4+1] = -__expf(v.y);
        A[q*4+2] = -__expf(v.z); A[q*4+3] = -__expf(v.w);
    }
    float h[16] = {};
    float P[16];
    #pragma unroll
    for (int n = 0; n < 16; ++n) P[n] = 1.f;

    const size_t row0 = (size_t)b * SEQ + c * TC;
    for (int t = 0; t < TC; ++t) {
        const size_t row = row0 + t;
        const float dtv = dt[row * D_MODEL + d];
        const float uv  = u[row * D_MODEL + d];
        float Bv[16];
        const float4* Bp = reinterpret_cast<const float4*>(&xdbl[row * XPROJ_N + DT_RANK]);
        #pragma unroll
        for (int q = 0; q < 4; ++q) {
            float4 v = Bp[q];
            Bv[q*4+0] = v.x; Bv[q*4+1] = v.y; Bv[q*4+2] = v.z; Bv[q*4+3] = v.w;
        }
        const float dtu = dtv * uv;
        #pragma unroll
        for (int n = 0; n < 16; ++n) {
            float dA = __expf(dtv * A[n]);
            h[n] = fmaf(dA, h[n], dtu * Bv[n]);
            P[n] *= dA;
        }
    }
    const size_t off = ((size_t)bc * D_MODEL + d) * 16;
    #pragma unroll
    for (int q = 0; q < 4; ++q) {
        *reinterpret_cast<float4*>(&PH[off + q*4])   =
            make_float4(P[q*4+0], P[q*4+1], P[q*4+2], P[q*4+3]);
        *reinterpret_cast<float4*>(&Hend[off + q*4]) =
            make_float4(h[q*4+0], h[q*4+1], h[q*4+2], h[q*4+3]);
    }
}

__global__ __launch_bounds__(256) void scan_part2(
    float* __restrict__ PH,
    const float* __restrict__ Hend)
{
    const int g  = blockIdx.x * 256 + threadIdx.x;
    const int b  = g >> 15;
    const int dn = g & 32767;
    float h = 0.f;
    #pragma unroll
    for (int c = 0; c < NC; ++c) {
        const size_t off = ((size_t)(b * NC + c) * D_MODEL * 16) + dn;
        const float p  = PH[off];
        const float he = Hend[off];
        PH[off] = h;
        h = fmaf(p, h, he);
    }
}

__global__ __launch_bounds__(256) void scan_part3(
    const float* __restrict__ dt,
    const float* __restrict__ xdbl,
    const float* __restrict__ xz,
    const float* __restrict__ u,
    const float* __restrict__ A_log,
    const float* __restrict__ Dskip,
    const float* __restrict__ PH,
    float* __restrict__ yact)
{
    const int tid = threadIdx.x;
    const int d   = blockIdx.x * 256 + tid;
    const int bc  = blockIdx.y;
    const int b   = bc >> 5;
    const int c   = bc & (NC - 1);

    float A[16];
    #pragma unroll
    for (int q = 0; q < 4; ++q) {
        float4 v = *reinterpret_cast<const float4*>(&A_log[d * 16 + q * 4]);
        A[q*4+0] = -__expf(v.x); A[q*4+1] = -__expf(v.y);
        A[q*4+2] = -__expf(v.z); A[q*4+3] = -__expf(v.w);
    }
    float h[16];
    const size_t off = ((size_t)bc * D_MODEL + d) * 16;
    #pragma unroll
    for (int q = 0; q < 4; ++q) {
        float4 v = *reinterpret_cast<const float4*>(&PH[off + q*4]);
        h[q*4+0] = v.x; h[q*4+1] = v.y; h[q*4+2] = v.z; h[q*4+3] = v.w;
    }
    const float Dk = Dskip[d];

    const size_t row0 = (size_t)b * SEQ + c * TC;
    for (int t = 0; t < TC; ++t) {
        const size_t row = row0 + t;
        const float dtv = dt[row * D_MODEL + d];
        const float uv  = u[row * D_MODEL + d];
        float Bv[16], Cv[16];
        const float4* Bp = reinterpret_cast<const float4*>(&xdbl[row * XPROJ_N + DT_RANK]);
        const float4* Cp = reinterpret_cast<const float4*>(&xdbl[row * XPROJ_N + DT_RANK + D_STATE]);
        #pragma unroll
        for (int q = 0; q < 4; ++q) {
            float4 v = Bp[q];
            Bv[q*4+0] = v.x; Bv[q*4+1] = v.y; Bv[q*4+2] = v.z; Bv[q*4+3] = v.w;
            float4 wv = Cp[q];
            Cv[q*4+0] = wv.x; Cv[q*4+1] = wv.y; Cv[q*4+2] = wv.z; Cv[q*4+3] = wv.w;
        }
        const float dtu = dtv * uv;
        float y = 0.f;
        #pragma unroll
        for (int n = 0; n < 16; ++n) {
            float dA = __expf(dtv * A[n]);
            h[n] = fmaf(dA, h[n], dtu * Bv[n]);
            y = fmaf(h[n], Cv[n], y);
        }
        const float zv = xz[row * (2 * D_MODEL) + D_MODEL + d];
        const float yv = y + uv * Dk;
        yact[row * D_MODEL + d] = yv * siluf(zv);
    }
}

// ---------------- launch ----------------
extern "C" void kernel_launch(void* const* d_in, const int* in_sizes, int n_in,
                              void* d_out, int out_size, void* d_ws, size_t ws_size,
                              hipStream_t stream) {
    const float* x       = (const float*)d_in[0];
    const float* W_in    = (const float*)d_in[1];
    const float* conv_w  = (const float*)d_in[2];
    const float* conv_b  = (const float*)d_in[3];
    const float* W_xproj = (const float*)d_in[4];
    const float* W_dt    = (const float*)d_in[5];
    const float* b_dt    = (const float*)d_in[6];
    const float* A_log   = (const float*)d_in[7];
    const float* Dskip   = (const float*)d_in[8];
    const float* W_out   = (const float*)d_in[9];
    float* out = (float*)d_out;

    float* ws = (float*)d_ws;
    const size_t M1 = 1024 * 1024;
    float* xz   = ws;                        // 8M fp32
    float* u    = ws + 8 * M1;               // 4M
    float* xdbl = ws + 12 * M1;              // 0.5M
    float* dt   = ws + 12 * M1 + 512 * 1024; // 4M
    float* yact = dt + 4 * M1;               // 4M
    float* PH   = yact + 4 * M1;             // 2M
    float* Hend = PH + 2 * M1;               // 2M  (ends at 24.5M floats)

    __bf16* planes = (__bf16*)(ws + 25 * M1);
    __bf16* xh  = planes;                    // 4M bf16
    __bf16* xl  = xh + 4 * M1;               // 4M
    __bf16* wih = xl + 4 * M1;               // 8M
    __bf16* wil = wih + 8 * M1;              // 8M  (ends at 25M + 12M floats)
    // reuse regions (stream-ordered; producers run after prior consumers):
    __bf16* woh = wih;                       // W_in planes dead after GEMM1
    __bf16* wol = wih + 4 * M1;
    __bf16* yh  = xh;                        // x planes dead after GEMM1
    __bf16* yl  = xl;
    float* xpart = (float*)(ws + 25 * M1);   // 2.62M floats, also in dead x-plane
                                             // region; consumed by xdbl_reduce
                                             // before yact split reuses it.

    // split x and W_in to bf16 hi/lo planes
    split_kernel<<<(BL * D_MODEL / 4 + 255) / 256, 256, 0, stream>>>(x, xh, xl, BL * D_MODEL / 4);
    split_kernel<<<(2 * D_MODEL * D_MODEL / 4 + 255) / 256, 256, 0, stream>>>(
        W_in, wih, wil, 2 * D_MODEL * D_MODEL / 4);

    // 1) xz = x @ W_in.T  (MFMA split-bf16)
    {
        dim3 grid(2 * D_MODEL / 128, BL / 128);
        gemm_bf3<<<grid, 256, 0, stream>>>(xh, xl, wih, wil, xz, 2 * D_MODEL, D_MODEL);
    }
    // 2) conv + silu
    conv_silu_kernel<<<BL * D_MODEL / 256, 256, 0, stream>>>(xz, conv_w, conv_b, u);

    // split W_out (reuses W_in plane region; GEMM1 already consumed it)
    split_kernel<<<(D_MODEL * D_MODEL / 4 + 255) / 256, 256, 0, stream>>>(
        W_out, woh, wol, D_MODEL * D_MODEL / 4);

    // 3) x_dbl = u @ W_xproj.T  (fp32 split-K; xpart overwrites dead x planes)
    {
        dim3 grid(XPROJ_N / XBN, BL / XBM, XKS);
        xdbl_partial<<<grid, 256, 0, stream>>>(u, W_xproj, xpart);
        xdbl_reduce<<<(BL * XPROJ_N / 4 + 255) / 256, 256, 0, stream>>>(xpart, xdbl);
    }
    // 4) dt = softplus(x_dbl[:, :128] @ W_dt.T + b_dt)  (fp32)
    {
        dim3 grid(D_MODEL / BN, BL / BM);
        gemm_nt<1><<<grid, 256, 0, stream>>>(xdbl, XPROJ_N, W_dt, DT_RANK,
                                             dt, D_MODEL, b_dt,
                                             BL, D_MODEL, DT_RANK);
    }
    // 5) chunked scan
    {
        dim3 grid(D_MODEL / 256, B_SZ * NC);
        scan_part1<<<grid, 256, 0, stream>>>(dt, xdbl, u, A_log, PH, Hend);
        scan_part2<<<B_SZ * D_MODEL * 16 / 256, 256, 0, stream>>>(PH, Hend);
        scan_part3<<<grid, 256, 0, stream>>>(dt, xdbl, xz, u, A_log, Dskip, PH, yact);
    }
    // split yact (reuses x-plane region after xpart is consumed)
    split_kernel<<<(BL * D_MODEL / 4 + 255) / 256, 256, 0, stream>>>(yact, yh, yl, BL * D_MODEL / 4);

    // 6) out = yact @ W_out.T  (MFMA split-bf16)
    {
        dim3 grid(D_MODEL / 128, BL / 128);
        gemm_bf3<<<grid, 256, 0, stream>>>(yh, yl, woh, wol, out, D_MODEL, D_MODEL);
    }
}

// Round 6
// 429.404 us; speedup vs baseline: 4.2592x; 1.0014x over previous
//
#include <hip/hip_runtime.h>
#include <hip/hip_bf16.h>

// Mamba block — split-bf16 MFMA GEMMs (double-buffered prefetch) + chunked scan.
//  1) xz = x @ W_in.T      (2048x4096, K=2048)  MFMA split-bf16  -> ws.xz (fp32)
//  2) u  = silu(conv4(xz[:, :2048]))                             -> ws.u
//  3) x_dbl = u @ W_xproj.T (2048x160, K=2048)  fp32 split-K(8)  -> ws.xdbl
//  4) dt = softplus(x_dbl[:,:128] @ W_dt.T + b_dt) fp32 VALU     -> ws.dt
//  5) chunked scan (S1/S2/S3), S3 emits yh/yl bf16 planes fused  -> ws.yh/yl
//  6) out = yact @ W_out.T (2048x2048, K=2048)  MFMA split-bf16  -> d_out

#define D_MODEL 2048
#define D_STATE 16
#define KER 4
#define DT_RANK 128
#define B_SZ 2
#define SEQ 1024
#define BL (B_SZ * SEQ)
#define XPROJ_N (DT_RANK + 2 * D_STATE)  // 160
#define NC 32
#define TC (SEQ / NC)

using f32x4  = __attribute__((ext_vector_type(4))) float;
using bf16x8 = __attribute__((ext_vector_type(8))) __bf16;
using bf16x4 = __attribute__((ext_vector_type(4))) __bf16;

__device__ __forceinline__ float softplusf(float x) {
    return (x > 20.f) ? x : log1pf(__expf(x));
}
__device__ __forceinline__ float siluf(float x) {
    return x / (1.f + __expf(-x));
}

// ---------------- fp32 -> (hi, lo) bf16 plane split ----------------
__global__ __launch_bounds__(256) void split_kernel(
    const float* __restrict__ src,
    __bf16* __restrict__ hi, __bf16* __restrict__ lo, int n4)
{
    int i = blockIdx.x * 256 + threadIdx.x;
    if (i >= n4) return;
    float4 v = *reinterpret_cast<const float4*>(&src[(size_t)i * 4]);
    bf16x4 hv, lv;
    float f[4] = {v.x, v.y, v.z, v.w};
    #pragma unroll
    for (int j = 0; j < 4; ++j) {
        __bf16 h = (__bf16)f[j];
        hv[j] = h;
        lv[j] = (__bf16)(f[j] - (float)h);
    }
    *reinterpret_cast<bf16x4*>(&hi[(size_t)i * 4]) = hv;
    *reinterpret_cast<bf16x4*>(&lo[(size_t)i * 4]) = lv;
}

// ---------------- split-bf16 MFMA NT GEMM, double-buffered ----------------
// C[m][n] = sum_k A[m,k]*W[n,k], A ~ Ah+Al, W ~ Wh+Wl (drop Al*Wl).
// 128x128 tile, BK=32, 4 waves (2x2 of 64x64), mfma_f32_16x16x32_bf16.
// LDS: 2 buffers x 4 planes x [128][32] bf16 = 64 KB. Prefetch pattern
// (T3 minimum 2-phase): STAGE(next buf) issued BEFORE compute(cur);
// __syncthreads() (drains vmcnt 0) lands the prefetch under the MFMAs.
// Row = 64B = 4 x 16B slots; XOR swizzle slot ^= (row>>1)&3 applied on BOTH
// global source (pre-swizzle) and ds_read (rule #21) -> uniform 2/bank.
__global__ __launch_bounds__(256, 2) void gemm_bf3(
    const __bf16* __restrict__ Ah, const __bf16* __restrict__ Al,
    const __bf16* __restrict__ Wh, const __bf16* __restrict__ Wl,
    float* __restrict__ C, int N_, int K)
{
    __shared__ __align__(16) __bf16 lds[2 * 4 * 128 * 32];  // 64 KB

    const int tid = threadIdx.x;
    const int bm = blockIdx.y * 128;
    const int bn = blockIdx.x * 128;
    const int w  = tid >> 6;
    const int l  = tid & 63;
    const int wr = (w >> 1) * 64;
    const int wc = (w & 1) * 64;
    const int fr = l & 15;
    const int fq = l >> 4;

    f32x4 acc[4][4] = {};

    // stage one K-tile (4 planes x 128x32 bf16) into buffer `buf`
    auto stage = [&](int buf, int k0) {
        __bf16* base = lds + buf * 16384;
        #pragma unroll
        for (int i = 0; i < 2; ++i) {
            const int f  = i * 256 + tid;          // 16B chunk 0..511
            const int r  = f >> 2;                 // tile row 0..127
            const int gs = (f & 3) ^ ((r >> 1) & 3);   // pre-swizzled src slot
            const size_t ga = (size_t)(bm + r) * K + k0 + gs * 8;
            const size_t gw = (size_t)(bn + r) * K + k0 + gs * 8;
            __builtin_amdgcn_global_load_lds(
                (const __attribute__((address_space(1))) void*)(Ah + ga),
                (__attribute__((address_space(3))) void*)(base + (size_t)f * 8), 16, 0, 0);
            __builtin_amdgcn_global_load_lds(
                (const __attribute__((address_space(1))) void*)(Al + ga),
                (__attribute__((address_space(3))) void*)(base + 4096 + (size_t)f * 8), 16, 0, 0);
            __builtin_amdgcn_global_load_lds(
                (const __attribute__((address_space(1))) void*)(Wh + gw),
                (__attribute__((address_space(3))) void*)(base + 8192 + (size_t)f * 8), 16, 0, 0);
            __builtin_amdgcn_global_load_lds(
                (const __attribute__((address_space(1))) void*)(Wl + gw),
                (__attribute__((address_space(3))) void*)(base + 12288 + (size_t)f * 8), 16, 0, 0);
        }
    };

    stage(0, 0);
    __syncthreads();                       // buf0 ready

    const int NT = K / 32;
    for (int kt = 0; kt < NT; ++kt) {
        const int cur = kt & 1;
        if (kt + 1 < NT) stage(cur ^ 1, (kt + 1) * 32);   // prefetch next

        const __bf16* base = lds + cur * 16384;
        bf16x8 ah[4], al[4], wh[4], wl[4];
        #pragma unroll
        for (int t = 0; t < 4; ++t) {
            const int ra = wr + t * 16 + fr;
            const int sa = fq ^ ((ra >> 1) & 3);
            ah[t] = *reinterpret_cast<const bf16x8*>(base + ra * 32 + sa * 8);
            al[t] = *reinterpret_cast<const bf16x8*>(base + 4096 + ra * 32 + sa * 8);
            const int rw = wc + t * 16 + fr;
            const int sw = fq ^ ((rw >> 1) & 3);
            wh[t] = *reinterpret_cast<const bf16x8*>(base + 8192 + rw * 32 + sw * 8);
            wl[t] = *reinterpret_cast<const bf16x8*>(base + 12288 + rw * 32 + sw * 8);
        }
        #pragma unroll
        for (int mt = 0; mt < 4; ++mt)
            #pragma unroll
            for (int nt = 0; nt < 4; ++nt) {
                acc[mt][nt] = __builtin_amdgcn_mfma_f32_16x16x32_bf16(
                    ah[mt], wh[nt], acc[mt][nt], 0, 0, 0);
                acc[mt][nt] = __builtin_amdgcn_mfma_f32_16x16x32_bf16(
                    ah[mt], wl[nt], acc[mt][nt], 0, 0, 0);
                acc[mt][nt] = __builtin_amdgcn_mfma_f32_16x16x32_bf16(
                    al[mt], wh[nt], acc[mt][nt], 0, 0, 0);
            }
        __syncthreads();   // drains vmcnt(0): prefetch landed; reads of cur done
    }

    // C/D layout (m89-verified): col = lane&15, row = (lane>>4)*4 + reg
    #pragma unroll
    for (int mt = 0; mt < 4; ++mt)
        #pragma unroll
        for (int nt = 0; nt < 4; ++nt)
            #pragma unroll
            for (int j = 0; j < 4; ++j)
                C[(size_t)(bm + wr + mt * 16 + fq * 4 + j) * N_
                  + bn + wc + nt * 16 + fr] = acc[mt][nt][j];
}

// ---------------- fp32 NT GEMM (dt GEMM) ----------------
#define BM 64
#define BN 64
#define BKT 32

template <int EPI>
__global__ __launch_bounds__(256) void gemm_nt(
    const float* __restrict__ A, int lda,
    const float* __restrict__ W, int ldw,
    float* __restrict__ C, int ldc,
    const float* __restrict__ bias,
    int M, int N, int K)
{
    __shared__ float As[BKT][BM + 4];
    __shared__ float Ws[BKT][BN + 4];

    const int tid = threadIdx.x;
    const int bm = blockIdx.y * BM;
    const int bn = blockIdx.x * BN;
    const int tx = tid & 15;
    const int ty = tid >> 4;

    float acc[4][4] = {};

    for (int k0 = 0; k0 < K; k0 += BKT) {
        #pragma unroll
        for (int i = 0; i < 2; ++i) {
            int f = tid + i * 256;
            int row = f >> 3;
            int kq  = f & 7;
            float4 v = *reinterpret_cast<const float4*>(
                &A[(size_t)(bm + row) * lda + k0 + kq * 4]);
            As[kq * 4 + 0][row] = v.x;
            As[kq * 4 + 1][row] = v.y;
            As[kq * 4 + 2][row] = v.z;
            As[kq * 4 + 3][row] = v.w;
        }
        #pragma unroll
        for (int i = 0; i < 2; ++i) {
            int f = tid + i * 256;
            int row = f >> 3;
            int kq  = f & 7;
            int gn = bn + row;
            float4 v = make_float4(0.f, 0.f, 0.f, 0.f);
            if (gn < N) {
                v = *reinterpret_cast<const float4*>(
                    &W[(size_t)gn * ldw + k0 + kq * 4]);
            }
            Ws[kq * 4 + 0][row] = v.x;
            Ws[kq * 4 + 1][row] = v.y;
            Ws[kq * 4 + 2][row] = v.z;
            Ws[kq * 4 + 3][row] = v.w;
        }
        __syncthreads();

        #pragma unroll
        for (int kk = 0; kk < BKT; ++kk) {
            float4 a4 = *reinterpret_cast<const float4*>(&As[kk][ty * 4]);
            float4 w4 = *reinterpret_cast<const float4*>(&Ws[kk][tx * 4]);
            float a[4] = {a4.x, a4.y, a4.z, a4.w};
            float wv[4] = {w4.x, w4.y, w4.z, w4.w};
            #pragma unroll
            for (int i = 0; i < 4; ++i)
                #pragma unroll
                for (int j = 0; j < 4; ++j)
                    acc[i][j] = fmaf(a[i], wv[j], acc[i][j]);
        }
        __syncthreads();
    }

    #pragma unroll
    for (int i = 0; i < 4; ++i) {
        int gm = bm + ty * 4 + i;
        #pragma unroll
        for (int j = 0; j < 4; ++j) {
            int gn = bn + tx * 4 + j;
            if (gn < N) {
                float v = acc[i][j];
                if (EPI == 1) v = softplusf(v + bias[gn]);
                C[(size_t)gm * ldc + gn] = v;
            }
        }
    }
}

// ---------------- split-K x_dbl GEMM: M=2048, N=160, K=2048 ----------------
#define XBM 64
#define XBN 32
#define XKS 8
#define XKC (D_MODEL / XKS)   // 256

__global__ __launch_bounds__(256) void xdbl_partial(
    const float* __restrict__ A,      // u (BL, D_MODEL)
    const float* __restrict__ W,      // W_xproj (160, D_MODEL)
    float* __restrict__ P)            // (XKS, BL, 160)
{
    __shared__ float As[BKT][XBM + 4];
    __shared__ float Ws[BKT][XBN + 4];

    const int tid = threadIdx.x;
    const int bm = blockIdx.y * XBM;
    const int bn = blockIdx.x * XBN;
    const int ks = blockIdx.z;
    const int tx = tid & 7;
    const int ty = tid >> 3;

    float acc[2][4] = {};

    const int kend = (ks + 1) * XKC;
    for (int k0 = ks * XKC; k0 < kend; k0 += BKT) {
        #pragma unroll
        for (int i = 0; i < 2; ++i) {
            int f = tid + i * 256;
            int row = f >> 3;
            int kq  = f & 7;
            float4 v = *reinterpret_cast<const float4*>(
                &A[(size_t)(bm + row) * D_MODEL + k0 + kq * 4]);
            As[kq * 4 + 0][row] = v.x;
            As[kq * 4 + 1][row] = v.y;
            As[kq * 4 + 2][row] = v.z;
            As[kq * 4 + 3][row] = v.w;
        }
        {
            int row = tid >> 3;
            int kq  = tid & 7;
            float4 v = *reinterpret_cast<const float4*>(
                &W[(size_t)(bn + row) * D_MODEL + k0 + kq * 4]);
            Ws[kq * 4 + 0][row] = v.x;
            Ws[kq * 4 + 1][row] = v.y;
            Ws[kq * 4 + 2][row] = v.z;
            Ws[kq * 4 + 3][row] = v.w;
        }
        __syncthreads();

        #pragma unroll
        for (int kk = 0; kk < BKT; ++kk) {
            float a0 = As[kk][ty * 2 + 0];
            float a1 = As[kk][ty * 2 + 1];
            float4 w4 = *reinterpret_cast<const float4*>(&Ws[kk][tx * 4]);
            float wv[4] = {w4.x, w4.y, w4.z, w4.w};
            #pragma unroll
            for (int j = 0; j < 4; ++j) {
                acc[0][j] = fmaf(a0, wv[j], acc[0][j]);
                acc[1][j] = fmaf(a1, wv[j], acc[1][j]);
            }
        }
        __syncthreads();
    }

    #pragma unroll
    for (int i = 0; i < 2; ++i) {
        const int gm = bm + ty * 2 + i;
        #pragma unroll
        for (int j = 0; j < 4; ++j) {
            const int gn = bn + tx * 4 + j;
            P[((size_t)ks * BL + gm) * XPROJ_N + gn] = acc[i][j];
        }
    }
}

__global__ __launch_bounds__(256) void xdbl_reduce(
    const float* __restrict__ P, float* __restrict__ xdbl)
{
    const int i = blockIdx.x * 256 + threadIdx.x;
    const int n4 = BL * XPROJ_N / 4;
    if (i >= n4) return;
    float4 s = *reinterpret_cast<const float4*>(&P[(size_t)i * 4]);
    #pragma unroll
    for (int ks = 1; ks < XKS; ++ks) {
        float4 v = *reinterpret_cast<const float4*>(
            &P[(size_t)ks * BL * XPROJ_N + (size_t)i * 4]);
        s.x += v.x; s.y += v.y; s.z += v.z; s.w += v.w;
    }
    *reinterpret_cast<float4*>(&xdbl[(size_t)i * 4]) = s;
}

// ---------------- depthwise causal conv (K=4) + SiLU ----------------
__global__ __launch_bounds__(256) void conv_silu_kernel(
    const float* __restrict__ xz,
    const float* __restrict__ conv_w,
    const float* __restrict__ conv_b,
    float* __restrict__ u)
{
    int idx = blockIdx.x * blockDim.x + threadIdx.x;
    if (idx >= BL * D_MODEL) return;
    int d  = idx & (D_MODEL - 1);
    int bl = idx >> 11;
    int l  = bl & (SEQ - 1);
    int b  = bl >> 10;

    float acc = conv_b[d];
    #pragma unroll
    for (int k = 0; k < KER; ++k) {
        int ls = l - (KER - 1) + k;
        if (ls >= 0) {
            acc = fmaf(conv_w[d * KER + k],
                       xz[(size_t)(b * SEQ + ls) * (2 * D_MODEL) + d], acc);
        }
    }
    u[(size_t)idx] = siluf(acc);
}

// ---------------- chunked selective scan ----------------
__global__ __launch_bounds__(256) void scan_part1(
    const float* __restrict__ dt,
    const float* __restrict__ xdbl,
    const float* __restrict__ u,
    const float* __restrict__ A_log,
    float* __restrict__ PH,
    float* __restrict__ Hend)
{
    const int tid = threadIdx.x;
    const int d   = blockIdx.x * 256 + tid;
    const int bc  = blockIdx.y;
    const int b   = bc >> 5;
    const int c   = bc & (NC - 1);

    float A[16];
    #pragma unroll
    for (int q = 0; q < 4; ++q) {
        float4 v = *reinterpret_cast<const float4*>(&A_log[d * 16 + q * 4]);
        A[q*4+0] = -__expf(v.x); A[q*4+1] = -__expf(v.y);
        A[q*4+2] = -__expf(v.z); A[q*4+3] = -__expf(v.w);
    }
    float h[16] = {};
    float P[16];
    #pragma unroll
    for (int n = 0; n < 16; ++n) P[n] = 1.f;

    const size_t row0 = (size_t)b * SEQ + c * TC;
    for (int t = 0; t < TC; ++t) {
        const size_t row = row0 + t;
        const float dtv = dt[row * D_MODEL + d];
        const float uv  = u[row * D_MODEL + d];
        float Bv[16];
        const float4* Bp = reinterpret_cast<const float4*>(&xdbl[row * XPROJ_N + DT_RANK]);
        #pragma unroll
        for (int q = 0; q < 4; ++q) {
            float4 v = Bp[q];
            Bv[q*4+0] = v.x; Bv[q*4+1] = v.y; Bv[q*4+2] = v.z; Bv[q*4+3] = v.w;
        }
        const float dtu = dtv * uv;
        #pragma unroll
        for (int n = 0; n < 16; ++n) {
            float dA = __expf(dtv * A[n]);
            h[n] = fmaf(dA, h[n], dtu * Bv[n]);
            P[n] *= dA;
        }
    }
    const size_t off = ((size_t)bc * D_MODEL + d) * 16;
    #pragma unroll
    for (int q = 0; q < 4; ++q) {
        *reinterpret_cast<float4*>(&PH[off + q*4])   =
            make_float4(P[q*4+0], P[q*4+1], P[q*4+2], P[q*4+3]);
        *reinterpret_cast<float4*>(&Hend[off + q*4]) =
            make_float4(h[q*4+0], h[q*4+1], h[q*4+2], h[q*4+3]);
    }
}

__global__ __launch_bounds__(256) void scan_part2(
    float* __restrict__ PH,
    const float* __restrict__ Hend)
{
    const int g  = blockIdx.x * 256 + threadIdx.x;
    const int b  = g >> 15;
    const int dn = g & 32767;
    float h = 0.f;
    #pragma unroll
    for (int c = 0; c < NC; ++c) {
        const size_t off = ((size_t)(b * NC + c) * D_MODEL * 16) + dn;
        const float p  = PH[off];
        const float he = Hend[off];
        PH[off] = h;
        h = fmaf(p, h, he);
    }
}

// S3: replay each chunk from its true Hstart; emit gated output directly as
// bf16 hi/lo planes (fused split — feeds GEMM6, saves one pass + dispatch).
__global__ __launch_bounds__(256) void scan_part3(
    const float* __restrict__ dt,
    const float* __restrict__ xdbl,
    const float* __restrict__ xz,
    const float* __restrict__ u,
    const float* __restrict__ A_log,
    const float* __restrict__ Dskip,
    const float* __restrict__ PH,
    __bf16* __restrict__ yh, __bf16* __restrict__ yl)
{
    const int tid = threadIdx.x;
    const int d   = blockIdx.x * 256 + tid;
    const int bc  = blockIdx.y;
    const int b   = bc >> 5;
    const int c   = bc & (NC - 1);

    float A[16];
    #pragma unroll
    for (int q = 0; q < 4; ++q) {
        float4 v = *reinterpret_cast<const float4*>(&A_log[d * 16 + q * 4]);
        A[q*4+0] = -__expf(v.x); A[q*4+1] = -__expf(v.y);
        A[q*4+2] = -__expf(v.z); A[q*4+3] = -__expf(v.w);
    }
    float h[16];
    const size_t off = ((size_t)bc * D_MODEL + d) * 16;
    #pragma unroll
    for (int q = 0; q < 4; ++q) {
        float4 v = *reinterpret_cast<const float4*>(&PH[off + q*4]);
        h[q*4+0] = v.x; h[q*4+1] = v.y; h[q*4+2] = v.z; h[q*4+3] = v.w;
    }
    const float Dk = Dskip[d];

    const size_t row0 = (size_t)b * SEQ + c * TC;
    for (int t = 0; t < TC; ++t) {
        const size_t row = row0 + t;
        const float dtv = dt[row * D_MODEL + d];
        const float uv  = u[row * D_MODEL + d];
        float Bv[16], Cv[16];
        const float4* Bp = reinterpret_cast<const float4*>(&xdbl[row * XPROJ_N + DT_RANK]);
        const float4* Cp = reinterpret_cast<const float4*>(&xdbl[row * XPROJ_N + DT_RANK + D_STATE]);
        #pragma unroll
        for (int q = 0; q < 4; ++q) {
            float4 v = Bp[q];
            Bv[q*4+0] = v.x; Bv[q*4+1] = v.y; Bv[q*4+2] = v.z; Bv[q*4+3] = v.w;
            float4 wv = Cp[q];
            Cv[q*4+0] = wv.x; Cv[q*4+1] = wv.y; Cv[q*4+2] = wv.z; Cv[q*4+3] = wv.w;
        }
        const float dtu = dtv * uv;
        float y = 0.f;
        #pragma unroll
        for (int n = 0; n < 16; ++n) {
            float dA = __expf(dtv * A[n]);
            h[n] = fmaf(dA, h[n], dtu * Bv[n]);
            y = fmaf(h[n], Cv[n], y);
        }
        const float zv = xz[row * (2 * D_MODEL) + D_MODEL + d];
        const float yv = (y + uv * Dk) * siluf(zv);
        const __bf16 hv = (__bf16)yv;
        yh[row * D_MODEL + d] = hv;
        yl[row * D_MODEL + d] = (__bf16)(yv - (float)hv);
    }
}

// ---------------- launch ----------------
extern "C" void kernel_launch(void* const* d_in, const int* in_sizes, int n_in,
                              void* d_out, int out_size, void* d_ws, size_t ws_size,
                              hipStream_t stream) {
    const float* x       = (const float*)d_in[0];
    const float* W_in    = (const float*)d_in[1];
    const float* conv_w  = (const float*)d_in[2];
    const float* conv_b  = (const float*)d_in[3];
    const float* W_xproj = (const float*)d_in[4];
    const float* W_dt    = (const float*)d_in[5];
    const float* b_dt    = (const float*)d_in[6];
    const float* A_log   = (const float*)d_in[7];
    const float* Dskip   = (const float*)d_in[8];
    const float* W_out   = (const float*)d_in[9];
    float* out = (float*)d_out;

    float* ws = (float*)d_ws;
    const size_t M1 = 1024 * 1024;
    float* xz   = ws;                        // 8M fp32
    float* u    = ws + 8 * M1;               // 4M
    float* xdbl = ws + 12 * M1;              // 0.5M
    float* dt   = ws + 12 * M1 + 512 * 1024; // 4M
    float* PH   = dt + 4 * M1;               // 2M
    float* Hend = PH + 2 * M1;               // 2M

    __bf16* planes = (__bf16*)(ws + 25 * M1);
    __bf16* xh  = planes;                    // 4M bf16
    __bf16* xl  = xh + 4 * M1;               // 4M
    __bf16* wih = xl + 4 * M1;               // 8M
    __bf16* wil = wih + 8 * M1;              // 8M
    // reuse regions (stream-ordered; producers run after prior consumers):
    __bf16* woh = wih;                       // W_in planes dead after GEMM1
    __bf16* wol = wih + 4 * M1;
    __bf16* yh  = xh;                        // x planes dead after GEMM1
    __bf16* yl  = xl;
    float* xpart = (float*)(ws + 25 * M1);   // dead x-plane region; consumed by
                                             // xdbl_reduce before scan_part3
                                             // writes yh/yl over it.

    // split x and W_in to bf16 hi/lo planes
    split_kernel<<<(BL * D_MODEL / 4 + 255) / 256, 256, 0, stream>>>(x, xh, xl, BL * D_MODEL / 4);
    split_kernel<<<(2 * D_MODEL * D_MODEL / 4 + 255) / 256, 256, 0, stream>>>(
        W_in, wih, wil, 2 * D_MODEL * D_MODEL / 4);

    // 1) xz = x @ W_in.T  (MFMA split-bf16, dbuf prefetch)
    {
        dim3 grid(2 * D_MODEL / 128, BL / 128);
        gemm_bf3<<<grid, 256, 0, stream>>>(xh, xl, wih, wil, xz, 2 * D_MODEL, D_MODEL);
    }
    // 2) conv + silu
    conv_silu_kernel<<<BL * D_MODEL / 256, 256, 0, stream>>>(xz, conv_w, conv_b, u);

    // split W_out (reuses W_in plane region; GEMM1 already consumed it)
    split_kernel<<<(D_MODEL * D_MODEL / 4 + 255) / 256, 256, 0, stream>>>(
        W_out, woh, wol, D_MODEL * D_MODEL / 4);

    // 3) x_dbl = u @ W_xproj.T  (fp32 split-K; xpart overwrites dead x planes)
    {
        dim3 grid(XPROJ_N / XBN, BL / XBM, XKS);
        xdbl_partial<<<grid, 256, 0, stream>>>(u, W_xproj, xpart);
        xdbl_reduce<<<(BL * XPROJ_N / 4 + 255) / 256, 256, 0, stream>>>(xpart, xdbl);
    }
    // 4) dt = softplus(x_dbl[:, :128] @ W_dt.T + b_dt)  (fp32)
    {
        dim3 grid(D_MODEL / BN, BL / BM);
        gemm_nt<1><<<grid, 256, 0, stream>>>(xdbl, XPROJ_N, W_dt, DT_RANK,
                                             dt, D_MODEL, b_dt,
                                             BL, D_MODEL, DT_RANK);
    }
    // 5) chunked scan; S3 emits yh/yl bf16 planes directly (fused split)
    {
        dim3 grid(D_MODEL / 256, B_SZ * NC);
        scan_part1<<<grid, 256, 0, stream>>>(dt, xdbl, u, A_log, PH, Hend);
        scan_part2<<<B_SZ * D_MODEL * 16 / 256, 256, 0, stream>>>(PH, Hend);
        scan_part3<<<grid, 256, 0, stream>>>(dt, xdbl, xz, u, A_log, Dskip, PH, yh, yl);
    }
    // 6) out = yact @ W_out.T  (MFMA split-bf16, dbuf prefetch)
    {
        dim3 grid(D_MODEL / 128, BL / 128);
        gemm_bf3<<<grid, 256, 0, stream>>>(yh, yl, woh, wol, out, D_MODEL, D_MODEL);
    }
}

// Round 7
// 403.461 us; speedup vs baseline: 4.5331x; 1.0643x over previous
//
#include <hip/hip_runtime.h>
#include <hip/hip_bf16.h>

// Mamba block — split-bf16 MFMA GEMMs (round-5 proven schedule) + chunked scan.
//  1) xz = x @ W_in.T      (2048x4096, K=2048)  MFMA split-bf16  -> ws.xz (fp32)
//  2) u  = silu(conv4(xz[:, :2048]))            vectorized x4    -> ws.u
//  3) x_dbl = u @ W_xproj.T (2048x160, K=2048)  fp32 split-K(8)  -> ws.xdbl
//  4) dt = softplus(x_dbl[:,:128] @ W_dt.T + b_dt) fp32 VALU     -> ws.dt
//  5) chunked scan (S1/S2/S3), S3 emits yh/yl bf16 planes fused  -> ws.yh/yl
//  6) out = yact @ W_out.T (2048x2048, K=2048)  MFMA split-bf16  -> d_out
//
// NOTE (round-6 post-mortem): BK=32 + prefetch-before-compute with
// __syncthreads() per step REGRESSED (MfmaUtil 55->47). __syncthreads drains
// vmcnt(0) anyway, so the prefetch bought nothing and barrier frequency
// doubled. This file restores the round-5 BK=64 schedule (83.5 us, 0 LDS
// bank conflicts via both-sides XOR swizzle slot^=(row&7)).

#define D_MODEL 2048
#define D_STATE 16
#define KER 4
#define DT_RANK 128
#define B_SZ 2
#define SEQ 1024
#define BL (B_SZ * SEQ)
#define XPROJ_N (DT_RANK + 2 * D_STATE)  // 160
#define NC 32
#define TC (SEQ / NC)

using f32x4  = __attribute__((ext_vector_type(4))) float;
using bf16x8 = __attribute__((ext_vector_type(8))) __bf16;
using bf16x4 = __attribute__((ext_vector_type(4))) __bf16;

__device__ __forceinline__ float softplusf(float x) {
    return (x > 20.f) ? x : log1pf(__expf(x));
}
__device__ __forceinline__ float siluf(float x) {
    return x / (1.f + __expf(-x));
}

// ---------------- fp32 -> (hi, lo) bf16 plane split ----------------
__global__ __launch_bounds__(256) void split_kernel(
    const float* __restrict__ src,
    __bf16* __restrict__ hi, __bf16* __restrict__ lo, int n4)
{
    int i = blockIdx.x * 256 + threadIdx.x;
    if (i >= n4) return;
    float4 v = *reinterpret_cast<const float4*>(&src[(size_t)i * 4]);
    bf16x4 hv, lv;
    float f[4] = {v.x, v.y, v.z, v.w};
    #pragma unroll
    for (int j = 0; j < 4; ++j) {
        __bf16 h = (__bf16)f[j];
        hv[j] = h;
        lv[j] = (__bf16)(f[j] - (float)h);
    }
    *reinterpret_cast<bf16x4*>(&hi[(size_t)i * 4]) = hv;
    *reinterpret_cast<bf16x4*>(&lo[(size_t)i * 4]) = lv;
}

// ---------------- split-bf16 MFMA NT GEMM (round-5 schedule) ----------------
// C[m][n] = sum_k A[m,k]*W[n,k], A ~ Ah+Al, W ~ Wh+Wl (drop Al*Wl).
// 128x128 tile, BK=64, 4 waves (2x2 of 64x64), mfma_f32_16x16x32_bf16.
// LDS linear row-major [128][64] bf16 per plane; XOR swizzle slot^=(row&7)
// applied on BOTH global source (pre-swizzle) and ds_read (rule #21).
__global__ __launch_bounds__(256, 2) void gemm_bf3(
    const __bf16* __restrict__ Ah, const __bf16* __restrict__ Al,
    const __bf16* __restrict__ Wh, const __bf16* __restrict__ Wl,
    float* __restrict__ C, int N_, int K)
{
    __shared__ __align__(16) __bf16 lds[4 * 128 * 64];
    __bf16* sAh = lds;
    __bf16* sAl = lds + 8192;
    __bf16* sWh = lds + 16384;
    __bf16* sWl = lds + 24576;

    const int tid = threadIdx.x;
    const int bm = blockIdx.y * 128;
    const int bn = blockIdx.x * 128;
    const int w  = tid >> 6;
    const int l  = tid & 63;
    const int wr = (w >> 1) * 64;
    const int wc = (w & 1) * 64;
    const int fr = l & 15;
    const int fq = l >> 4;

    f32x4 acc[4][4] = {};

    for (int k0 = 0; k0 < K; k0 += 64) {
        #pragma unroll
        for (int i = 0; i < 4; ++i) {
            const int f  = i * 256 + tid;   // 16B chunk id 0..1023
            const int r  = f >> 3;          // tile row 0..127
            const int ss = f & 7;           // dest slot
            const int gs = ss ^ (r & 7);    // pre-swizzled source slot
            const size_t ga = (size_t)(bm + r) * K + k0 + gs * 8;
            const size_t gw = (size_t)(bn + r) * K + k0 + gs * 8;
            __builtin_amdgcn_global_load_lds(
                (const __attribute__((address_space(1))) void*)(Ah + ga),
                (__attribute__((address_space(3))) void*)(sAh + (size_t)f * 8), 16, 0, 0);
            __builtin_amdgcn_global_load_lds(
                (const __attribute__((address_space(1))) void*)(Al + ga),
                (__attribute__((address_space(3))) void*)(sAl + (size_t)f * 8), 16, 0, 0);
            __builtin_amdgcn_global_load_lds(
                (const __attribute__((address_space(1))) void*)(Wh + gw),
                (__attribute__((address_space(3))) void*)(sWh + (size_t)f * 8), 16, 0, 0);
            __builtin_amdgcn_global_load_lds(
                (const __attribute__((address_space(1))) void*)(Wl + gw),
                (__attribute__((address_space(3))) void*)(sWl + (size_t)f * 8), 16, 0, 0);
        }
        __syncthreads();

        #pragma unroll
        for (int ks = 0; ks < 2; ++ks) {
            bf16x8 ah[4], al[4], wh[4], wl[4];
            #pragma unroll
            for (int t = 0; t < 4; ++t) {
                const int ra = wr + t * 16 + fr;
                const int sa = (ks * 4 + fq) ^ (ra & 7);
                ah[t] = *reinterpret_cast<const bf16x8*>(&sAh[ra * 64 + sa * 8]);
                al[t] = *reinterpret_cast<const bf16x8*>(&sAl[ra * 64 + sa * 8]);
                const int rw = wc + t * 16 + fr;
                const int sw = (ks * 4 + fq) ^ (rw & 7);
                wh[t] = *reinterpret_cast<const bf16x8*>(&sWh[rw * 64 + sw * 8]);
                wl[t] = *reinterpret_cast<const bf16x8*>(&sWl[rw * 64 + sw * 8]);
            }
            #pragma unroll
            for (int mt = 0; mt < 4; ++mt)
                #pragma unroll
                for (int nt = 0; nt < 4; ++nt) {
                    acc[mt][nt] = __builtin_amdgcn_mfma_f32_16x16x32_bf16(
                        ah[mt], wh[nt], acc[mt][nt], 0, 0, 0);
                    acc[mt][nt] = __builtin_amdgcn_mfma_f32_16x16x32_bf16(
                        ah[mt], wl[nt], acc[mt][nt], 0, 0, 0);
                    acc[mt][nt] = __builtin_amdgcn_mfma_f32_16x16x32_bf16(
                        al[mt], wh[nt], acc[mt][nt], 0, 0, 0);
                }
        }
        __syncthreads();
    }

    // C/D layout (m89-verified): col = lane&15, row = (lane>>4)*4 + reg
    #pragma unroll
    for (int mt = 0; mt < 4; ++mt)
        #pragma unroll
        for (int nt = 0; nt < 4; ++nt)
            #pragma unroll
            for (int j = 0; j < 4; ++j)
                C[(size_t)(bm + wr + mt * 16 + fq * 4 + j) * N_
                  + bn + wc + nt * 16 + fr] = acc[mt][nt][j];
}

// ---------------- fp32 NT GEMM (dt GEMM) ----------------
#define BM 64
#define BN 64
#define BKT 32

template <int EPI>
__global__ __launch_bounds__(256) void gemm_nt(
    const float* __restrict__ A, int lda,
    const float* __restrict__ W, int ldw,
    float* __restrict__ C, int ldc,
    const float* __restrict__ bias,
    int M, int N, int K)
{
    __shared__ float As[BKT][BM + 4];
    __shared__ float Ws[BKT][BN + 4];

    const int tid = threadIdx.x;
    const int bm = blockIdx.y * BM;
    const int bn = blockIdx.x * BN;
    const int tx = tid & 15;
    const int ty = tid >> 4;

    float acc[4][4] = {};

    for (int k0 = 0; k0 < K; k0 += BKT) {
        #pragma unroll
        for (int i = 0; i < 2; ++i) {
            int f = tid + i * 256;
            int row = f >> 3;
            int kq  = f & 7;
            float4 v = *reinterpret_cast<const float4*>(
                &A[(size_t)(bm + row) * lda + k0 + kq * 4]);
            As[kq * 4 + 0][row] = v.x;
            As[kq * 4 + 1][row] = v.y;
            As[kq * 4 + 2][row] = v.z;
            As[kq * 4 + 3][row] = v.w;
        }
        #pragma unroll
        for (int i = 0; i < 2; ++i) {
            int f = tid + i * 256;
            int row = f >> 3;
            int kq  = f & 7;
            int gn = bn + row;
            float4 v = make_float4(0.f, 0.f, 0.f, 0.f);
            if (gn < N) {
                v = *reinterpret_cast<const float4*>(
                    &W[(size_t)gn * ldw + k0 + kq * 4]);
            }
            Ws[kq * 4 + 0][row] = v.x;
            Ws[kq * 4 + 1][row] = v.y;
            Ws[kq * 4 + 2][row] = v.z;
            Ws[kq * 4 + 3][row] = v.w;
        }
        __syncthreads();

        #pragma unroll
        for (int kk = 0; kk < BKT; ++kk) {
            float4 a4 = *reinterpret_cast<const float4*>(&As[kk][ty * 4]);
            float4 w4 = *reinterpret_cast<const float4*>(&Ws[kk][tx * 4]);
            float a[4] = {a4.x, a4.y, a4.z, a4.w};
            float wv[4] = {w4.x, w4.y, w4.z, w4.w};
            #pragma unroll
            for (int i = 0; i < 4; ++i)
                #pragma unroll
                for (int j = 0; j < 4; ++j)
                    acc[i][j] = fmaf(a[i], wv[j], acc[i][j]);
        }
        __syncthreads();
    }

    #pragma unroll
    for (int i = 0; i < 4; ++i) {
        int gm = bm + ty * 4 + i;
        #pragma unroll
        for (int j = 0; j < 4; ++j) {
            int gn = bn + tx * 4 + j;
            if (gn < N) {
                float v = acc[i][j];
                if (EPI == 1) v = softplusf(v + bias[gn]);
                C[(size_t)gm * ldc + gn] = v;
            }
        }
    }
}

// ---------------- split-K x_dbl GEMM: M=2048, N=160, K=2048 ----------------
#define XBM 64
#define XBN 32
#define XKS 8
#define XKC (D_MODEL / XKS)   // 256

__global__ __launch_bounds__(256) void xdbl_partial(
    const float* __restrict__ A,      // u (BL, D_MODEL)
    const float* __restrict__ W,      // W_xproj (160, D_MODEL)
    float* __restrict__ P)            // (XKS, BL, 160)
{
    __shared__ float As[BKT][XBM + 4];
    __shared__ float Ws[BKT][XBN + 4];

    const int tid = threadIdx.x;
    const int bm = blockIdx.y * XBM;
    const int bn = blockIdx.x * XBN;
    const int ks = blockIdx.z;
    const int tx = tid & 7;
    const int ty = tid >> 3;

    float acc[2][4] = {};

    const int kend = (ks + 1) * XKC;
    for (int k0 = ks * XKC; k0 < kend; k0 += BKT) {
        #pragma unroll
        for (int i = 0; i < 2; ++i) {
            int f = tid + i * 256;
            int row = f >> 3;
            int kq  = f & 7;
            float4 v = *reinterpret_cast<const float4*>(
                &A[(size_t)(bm + row) * D_MODEL + k0 + kq * 4]);
            As[kq * 4 + 0][row] = v.x;
            As[kq * 4 + 1][row] = v.y;
            As[kq * 4 + 2][row] = v.z;
            As[kq * 4 + 3][row] = v.w;
        }
        {
            int row = tid >> 3;
            int kq  = tid & 7;
            float4 v = *reinterpret_cast<const float4*>(
                &W[(size_t)(bn + row) * D_MODEL + k0 + kq * 4]);
            Ws[kq * 4 + 0][row] = v.x;
            Ws[kq * 4 + 1][row] = v.y;
            Ws[kq * 4 + 2][row] = v.z;
            Ws[kq * 4 + 3][row] = v.w;
        }
        __syncthreads();

        #pragma unroll
        for (int kk = 0; kk < BKT; ++kk) {
            float a0 = As[kk][ty * 2 + 0];
            float a1 = As[kk][ty * 2 + 1];
            float4 w4 = *reinterpret_cast<const float4*>(&Ws[kk][tx * 4]);
            float wv[4] = {w4.x, w4.y, w4.z, w4.w};
            #pragma unroll
            for (int j = 0; j < 4; ++j) {
                acc[0][j] = fmaf(a0, wv[j], acc[0][j]);
                acc[1][j] = fmaf(a1, wv[j], acc[1][j]);
            }
        }
        __syncthreads();
    }

    #pragma unroll
    for (int i = 0; i < 2; ++i) {
        const int gm = bm + ty * 2 + i;
        #pragma unroll
        for (int j = 0; j < 4; ++j) {
            const int gn = bn + tx * 4 + j;
            P[((size_t)ks * BL + gm) * XPROJ_N + gn] = acc[i][j];
        }
    }
}

__global__ __launch_bounds__(256) void xdbl_reduce(
    const float* __restrict__ P, float* __restrict__ xdbl)
{
    const int i = blockIdx.x * 256 + threadIdx.x;
    const int n4 = BL * XPROJ_N / 4;
    if (i >= n4) return;
    float4 s = *reinterpret_cast<const float4*>(&P[(size_t)i * 4]);
    #pragma unroll
    for (int ks = 1; ks < XKS; ++ks) {
        float4 v = *reinterpret_cast<const float4*>(
            &P[(size_t)ks * BL * XPROJ_N + (size_t)i * 4]);
        s.x += v.x; s.y += v.y; s.z += v.z; s.w += v.w;
    }
    *reinterpret_cast<float4*>(&xdbl[(size_t)i * 4]) = s;
}

// ------------- depthwise causal conv (K=4) + SiLU, 4 channels/thread -------------
__global__ __launch_bounds__(256) void conv_silu_kernel(
    const float* __restrict__ xz,      // (BL, 4096); u_raw = cols [0, 2048)
    const float* __restrict__ conv_w,  // (D, 4)
    const float* __restrict__ conv_b,  // (D,)
    float* __restrict__ u)             // (BL, D)
{
    int idx = blockIdx.x * 256 + threadIdx.x;      // over BL * D/4
    if (idx >= BL * (D_MODEL / 4)) return;
    const int d4 = (idx & (D_MODEL / 4 - 1)) * 4;
    const int bl = idx >> 9;                        // / (D/4)
    const int l  = bl & (SEQ - 1);
    const int b  = bl >> 10;

    float4 cb = *reinterpret_cast<const float4*>(&conv_b[d4]);
    float4 cw[4];
    #pragma unroll
    for (int j = 0; j < 4; ++j)
        cw[j] = *reinterpret_cast<const float4*>(&conv_w[(d4 + j) * KER]);

    float acc[4] = {cb.x, cb.y, cb.z, cb.w};
    #pragma unroll
    for (int k = 0; k < KER; ++k) {
        const int ls = l - (KER - 1) + k;
        if (ls >= 0) {
            float4 v = *reinterpret_cast<const float4*>(
                &xz[(size_t)(b * SEQ + ls) * (2 * D_MODEL) + d4]);
            acc[0] = fmaf((&cw[0].x)[k], v.x, acc[0]);
            acc[1] = fmaf((&cw[1].x)[k], v.y, acc[1]);
            acc[2] = fmaf((&cw[2].x)[k], v.z, acc[2]);
            acc[3] = fmaf((&cw[3].x)[k], v.w, acc[3]);
        }
    }
    float4 o;
    o.x = siluf(acc[0]); o.y = siluf(acc[1]);
    o.z = siluf(acc[2]); o.w = siluf(acc[3]);
    *reinterpret_cast<float4*>(&u[(size_t)bl * D_MODEL + d4]) = o;
}

// ---------------- chunked selective scan ----------------
__global__ __launch_bounds__(256) void scan_part1(
    const float* __restrict__ dt,
    const float* __restrict__ xdbl,
    const float* __restrict__ u,
    const float* __restrict__ A_log,
    float* __restrict__ PH,
    float* __restrict__ Hend)
{
    const int tid = threadIdx.x;
    const int d   = blockIdx.x * 256 + tid;
    const int bc  = blockIdx.y;
    const int b   = bc >> 5;
    const int c   = bc & (NC - 1);

    float A[16];
    #pragma unroll
    for (int q = 0; q < 4; ++q) {
        float4 v = *reinterpret_cast<const float4*>(&A_log[d * 16 + q * 4]);
        A[q*4+0] = -__expf(v.x); A[q*4+1] = -__expf(v.y);
        A[q*4+2] = -__expf(v.z); A[q*4+3] = -__expf(v.w);
    }
    float h[16] = {};
    float P[16];
    #pragma unroll
    for (int n = 0; n < 16; ++n) P[n] = 1.f;

    const size_t row0 = (size_t)b * SEQ + c * TC;
    for (int t = 0; t < TC; ++t) {
        const size_t row = row0 + t;
        const float dtv = dt[row * D_MODEL + d];
        const float uv  = u[row * D_MODEL + d];
        float Bv[16];
        const float4* Bp = reinterpret_cast<const float4*>(&xdbl[row * XPROJ_N + DT_RANK]);
        #pragma unroll
        for (int q = 0; q < 4; ++q) {
            float4 v = Bp[q];
            Bv[q*4+0] = v.x; Bv[q*4+1] = v.y; Bv[q*4+2] = v.z; Bv[q*4+3] = v.w;
        }
        const float dtu = dtv * uv;
        #pragma unroll
        for (int n = 0; n < 16; ++n) {
            float dA = __expf(dtv * A[n]);
            h[n] = fmaf(dA, h[n], dtu * Bv[n]);
            P[n] *= dA;
        }
    }
    const size_t off = ((size_t)bc * D_MODEL + d) * 16;
    #pragma unroll
    for (int q = 0; q < 4; ++q) {
        *reinterpret_cast<float4*>(&PH[off + q*4])   =
            make_float4(P[q*4+0], P[q*4+1], P[q*4+2], P[q*4+3]);
        *reinterpret_cast<float4*>(&Hend[off + q*4]) =
            make_float4(h[q*4+0], h[q*4+1], h[q*4+2], h[q*4+3]);
    }
}

__global__ __launch_bounds__(256) void scan_part2(
    float* __restrict__ PH,
    const float* __restrict__ Hend)
{
    const int g  = blockIdx.x * 256 + threadIdx.x;
    const int b  = g >> 15;
    const int dn = g & 32767;
    float h = 0.f;
    #pragma unroll
    for (int c = 0; c < NC; ++c) {
        const size_t off = ((size_t)(b * NC + c) * D_MODEL * 16) + dn;
        const float p  = PH[off];
        const float he = Hend[off];
        PH[off] = h;
        h = fmaf(p, h, he);
    }
}

// S3: replay each chunk from its true Hstart; emit gated output directly as
// bf16 hi/lo planes (fused split — feeds GEMM6, saves one pass + dispatch).
__global__ __launch_bounds__(256) void scan_part3(
    const float* __restrict__ dt,
    const float* __restrict__ xdbl,
    const float* __restrict__ xz,
    const float* __restrict__ u,
    const float* __restrict__ A_log,
    const float* __restrict__ Dskip,
    const float* __restrict__ PH,
    __bf16* __restrict__ yh, __bf16* __restrict__ yl)
{
    const int tid = threadIdx.x;
    const int d   = blockIdx.x * 256 + tid;
    const int bc  = blockIdx.y;
    const int b   = bc >> 5;
    const int c   = bc & (NC - 1);

    float A[16];
    #pragma unroll
    for (int q = 0; q < 4; ++q) {
        float4 v = *reinterpret_cast<const float4*>(&A_log[d * 16 + q * 4]);
        A[q*4+0] = -__expf(v.x); A[q*4+1] = -__expf(v.y);
        A[q*4+2] = -__expf(v.z); A[q*4+3] = -__expf(v.w);
    }
    float h[16];
    const size_t off = ((size_t)bc * D_MODEL + d) * 16;
    #pragma unroll
    for (int q = 0; q < 4; ++q) {
        float4 v = *reinterpret_cast<const float4*>(&PH[off + q*4]);
        h[q*4+0] = v.x; h[q*4+1] = v.y; h[q*4+2] = v.z; h[q*4+3] = v.w;
    }
    const float Dk = Dskip[d];

    const size_t row0 = (size_t)b * SEQ + c * TC;
    for (int t = 0; t < TC; ++t) {
        const size_t row = row0 + t;
        const float dtv = dt[row * D_MODEL + d];
        const float uv  = u[row * D_MODEL + d];
        float Bv[16], Cv[16];
        const float4* Bp = reinterpret_cast<const float4*>(&xdbl[row * XPROJ_N + DT_RANK]);
        const float4* Cp = reinterpret_cast<const float4*>(&xdbl[row * XPROJ_N + DT_RANK + D_STATE]);
        #pragma unroll
        for (int q = 0; q < 4; ++q) {
            float4 v = Bp[q];
            Bv[q*4+0] = v.x; Bv[q*4+1] = v.y; Bv[q*4+2] = v.z; Bv[q*4+3] = v.w;
            float4 wv = Cp[q];
            Cv[q*4+0] = wv.x; Cv[q*4+1] = wv.y; Cv[q*4+2] = wv.z; Cv[q*4+3] = wv.w;
        }
        const float dtu = dtv * uv;
        float y = 0.f;
        #pragma unroll
        for (int n = 0; n < 16; ++n) {
            float dA = __expf(dtv * A[n]);
            h[n] = fmaf(dA, h[n], dtu * Bv[n]);
            y = fmaf(h[n], Cv[n], y);
        }
        const float zv = xz[row * (2 * D_MODEL) + D_MODEL + d];
        const float yv = (y + uv * Dk) * siluf(zv);
        const __bf16 hv = (__bf16)yv;
        yh[row * D_MODEL + d] = hv;
        yl[row * D_MODEL + d] = (__bf16)(yv - (float)hv);
    }
}

// ---------------- launch ----------------
extern "C" void kernel_launch(void* const* d_in, const int* in_sizes, int n_in,
                              void* d_out, int out_size, void* d_ws, size_t ws_size,
                              hipStream_t stream) {
    const float* x       = (const float*)d_in[0];
    const float* W_in    = (const float*)d_in[1];
    const float* conv_w  = (const float*)d_in[2];
    const float* conv_b  = (const float*)d_in[3];
    const float* W_xproj = (const float*)d_in[4];
    const float* W_dt    = (const float*)d_in[5];
    const float* b_dt    = (const float*)d_in[6];
    const float* A_log   = (const float*)d_in[7];
    const float* Dskip   = (const float*)d_in[8];
    const float* W_out   = (const float*)d_in[9];
    float* out = (float*)d_out;

    float* ws = (float*)d_ws;
    const size_t M1 = 1024 * 1024;
    float* xz   = ws;                        // 8M fp32
    float* u    = ws + 8 * M1;               // 4M
    float* xdbl = ws + 12 * M1;              // 0.5M
    float* dt   = ws + 12 * M1 + 512 * 1024; // 4M
    float* PH   = dt + 4 * M1;               // 2M
    float* Hend = PH + 2 * M1;               // 2M

    __bf16* planes = (__bf16*)(ws + 25 * M1);
    __bf16* xh  = planes;                    // 4M bf16
    __bf16* xl  = xh + 4 * M1;               // 4M
    __bf16* wih = xl + 4 * M1;               // 8M
    __bf16* wil = wih + 8 * M1;              // 8M
    // reuse regions (stream-ordered; producers run after prior consumers):
    __bf16* woh = wih;                       // W_in planes dead after GEMM1
    __bf16* wol = wih + 4 * M1;
    __bf16* yh  = xh;                        // x planes dead after GEMM1
    __bf16* yl  = xl;
    float* xpart = (float*)(ws + 25 * M1);   // dead x-plane region; consumed by
                                             // xdbl_reduce before scan_part3
                                             // writes yh/yl over it.

    // split x and W_in to bf16 hi/lo planes
    split_kernel<<<(BL * D_MODEL / 4 + 255) / 256, 256, 0, stream>>>(x, xh, xl, BL * D_MODEL / 4);
    split_kernel<<<(2 * D_MODEL * D_MODEL / 4 + 255) / 256, 256, 0, stream>>>(
        W_in, wih, wil, 2 * D_MODEL * D_MODEL / 4);

    // 1) xz = x @ W_in.T  (MFMA split-bf16)
    {
        dim3 grid(2 * D_MODEL / 128, BL / 128);
        gemm_bf3<<<grid, 256, 0, stream>>>(xh, xl, wih, wil, xz, 2 * D_MODEL, D_MODEL);
    }
    // 2) conv + silu (vectorized x4)
    conv_silu_kernel<<<BL * (D_MODEL / 4) / 256, 256, 0, stream>>>(xz, conv_w, conv_b, u);

    // split W_out (reuses W_in plane region; GEMM1 already consumed it)
    split_kernel<<<(D_MODEL * D_MODEL / 4 + 255) / 256, 256, 0, stream>>>(
        W_out, woh, wol, D_MODEL * D_MODEL / 4);

    // 3) x_dbl = u @ W_xproj.T  (fp32 split-K; xpart overwrites dead x planes)
    {
        dim3 grid(XPROJ_N / XBN, BL / XBM, XKS);
        xdbl_partial<<<grid, 256, 0, stream>>>(u, W_xproj, xpart);
        xdbl_reduce<<<(BL * XPROJ_N / 4 + 255) / 256, 256, 0, stream>>>(xpart, xdbl);
    }
    // 4) dt = softplus(x_dbl[:, :128] @ W_dt.T + b_dt)  (fp32)
    {
        dim3 grid(D_MODEL / BN, BL / BM);
        gemm_nt<1><<<grid, 256, 0, stream>>>(xdbl, XPROJ_N, W_dt, DT_RANK,
                                             dt, D_MODEL, b_dt,
                                             BL, D_MODEL, DT_RANK);
    }
    // 5) chunked scan; S3 emits yh/yl bf16 planes directly (fused split)
    {
        dim3 grid(D_MODEL / 256, B_SZ * NC);
        scan_part1<<<grid, 256, 0, stream>>>(dt, xdbl, u, A_log, PH, Hend);
        scan_part2<<<B_SZ * D_MODEL * 16 / 256, 256, 0, stream>>>(PH, Hend);
        scan_part3<<<grid, 256, 0, stream>>>(dt, xdbl, xz, u, A_log, Dskip, PH, yh, yl);
    }
    // 6) out = yact @ W_out.T  (MFMA split-bf16)
    {
        dim3 grid(D_MODEL / 128, BL / 128);
        gemm_bf3<<<grid, 256, 0, stream>>>(yh, yl, woh, wol, out, D_MODEL, D_MODEL);
    }
}